// Round 6
// baseline (2212.999 us; speedup 1.0000x reference)
//
#include <hip/hip_runtime.h>

// LinearRNN: ys[t] = A^(t+1) @ y_init[0], t = 0..8191, D = 2048.
// Row-vector convention: T = A^T, rows[t] = y1 * T^(t+1).
// fp32 -> 3 bf16 limbs (h,m,l); 6 limb-product MFMAs ~= fp32 GEMM.
// R6: v_mfma_f32_32x32x16_bf16 (2x FLOP/operand-byte, 2382 TF ceiling) with
// split-K waves: block 128x128, 8 waves = 2M x 2N x 2K, wave tile 64x64, each
// wave owns a K=16 half of each BK=32 step. LDS reads 96KB/block-step < MFMA
// 1550 cyc -> MFMA-bound. K-halves merged via one 64KB LDS reduction at end.
// Fragment-packed global operands (1KB = 32x16 frag = 64 lanes x 16B); linear
// global_load_lds staging; ds_read_b128 frag_base + lane*16 (0 conflicts).

#define D 2048
#define STEPS 8192
#define KB2 2048

typedef __attribute__((ext_vector_type(8))) short short8;
typedef __attribute__((ext_vector_type(4))) float f32x4;
typedef __attribute__((ext_vector_type(16))) float f32x16;
typedef __attribute__((ext_vector_type(4))) unsigned short ushort4v;
typedef __attribute__((ext_vector_type(8))) unsigned short ushort8v;
typedef unsigned short ushort;

__device__ __forceinline__ ushort bf16_rne(float v) {
    unsigned u = __builtin_bit_cast(unsigned, v);
    u += 0x7fffu + ((u >> 16) & 1u);
    return (ushort)(u >> 16);
}
__device__ __forceinline__ float bf16_to_f(ushort h) {
    unsigned u = (unsigned)h << 16;
    return __builtin_bit_cast(float, u);
}

// Packed addresses (elements). Fragment = 32 rows/cols x 16 k = 512 elems.
// PA: [rb=r>>7][kt=k>>5][L][ks=(k>>4)&1][rf=(r>>5)&3][lane=(r&31)+32*((k>>3)&1)][e=k&7]
__device__ __forceinline__ size_t pa32_addr(int r, int k, int L) {
    return (size_t)((r >> 7) * 64 + (k >> 5)) * 12288
         + (size_t)(((L * 2 + ((k >> 4) & 1)) * 4 + ((r >> 5) & 3)) * 512
                    + ((r & 31) + 32 * ((k >> 3) & 1)) * 8 + (k & 7));
}
// PB: [cb=c>>7][kt=k>>5][L][ks][cf=(c>>5)&3][lane=(c&31)+32*((k>>3)&1)][e=k&7]
__device__ __forceinline__ size_t pb32_addr(int c, int k, int L) {
    return (size_t)((c >> 7) * 64 + (k >> 5)) * 12288
         + (size_t)(((L * 2 + ((k >> 4) & 1)) * 4 + ((c >> 5) & 3)) * 512
                    + ((c & 31) + 32 * ((k >> 3) & 1)) * 8 + (k & 7));
}

__device__ __forceinline__ ushort8v mk8(const ushort* p) {
    ushort8v v = {p[0], p[1], p[2], p[3], p[4], p[5], p[6], p[7]};
    return v;
}

__device__ __forceinline__ void gload16(const void* g, void* l) {
    __builtin_amdgcn_global_load_lds(
        (const __attribute__((address_space(1))) unsigned int*)g,
        (__attribute__((address_space(3))) unsigned int*)l, 16, 0, 0);
}

template<int N> __device__ __forceinline__ void vmwait();
template<> __device__ __forceinline__ void vmwait<0>() { asm volatile("s_waitcnt vmcnt(0)" ::: "memory"); }
template<> __device__ __forceinline__ void vmwait<6>() { asm volatile("s_waitcnt vmcnt(6)" ::: "memory"); }
__device__ __forceinline__ void lgkm0() { asm volatile("s_waitcnt lgkmcnt(0)" ::: "memory"); }
__device__ __forceinline__ void barfence() {
    __builtin_amdgcn_sched_barrier(0);
    __builtin_amdgcn_s_barrier();
    __builtin_amdgcn_sched_barrier(0);
}

// ---------------- prep: A -> PA-packed of T and PB-packed of T ----------------
// PA(r,k) = T[r][k] = A[k][r];  PB(c,k) = T[k][c] = A[c][k].
__global__ __launch_bounds__(256) void prep_pack(const float* __restrict__ A,
                                                 ushort* PA, ushort* PB) {
    __shared__ float tile[64][65];
    const int tid = threadIdx.x;
    const int bx = blockIdx.x * 64, by = blockIdx.y * 64;
    {
        const int rl = tid >> 2, cq = (tid & 3) * 16;
        const float* src = &A[(size_t)(by + rl) * D + bx + cq];
#pragma unroll
        for (int i = 0; i < 4; ++i) {
            float4 v = *reinterpret_cast<const float4*>(src + i * 4);
            tile[rl][cq + i * 4 + 0] = v.x;
            tile[rl][cq + i * 4 + 1] = v.y;
            tile[rl][cq + i * 4 + 2] = v.z;
            tile[rl][cq + i * 4 + 3] = v.w;
        }
    }
    __syncthreads();
    const int off = tid & 63, kc = tid >> 6;
    ushort hb[16], mb[16], lb[16];
    // PA: r = bx+off, k = by+kc*16+kk, val = A[k][r]
#pragma unroll
    for (int kk = 0; kk < 16; ++kk) {
        const float x = tile[kc * 16 + kk][off];
        const ushort h = bf16_rne(x); const float r1 = x - bf16_to_f(h);
        const ushort md = bf16_rne(r1); const float r2 = r1 - bf16_to_f(md);
        hb[kk] = h; mb[kk] = md; lb[kk] = bf16_rne(r2);
    }
#pragma unroll
    for (int g = 0; g < 2; ++g) {
        const size_t a0 = pa32_addr(bx + off, by + kc * 16 + g * 8, 0);
        *(ushort8v*)&PA[a0]        = mk8(hb + g * 8);
        *(ushort8v*)&PA[a0 + 4096] = mk8(mb + g * 8);
        *(ushort8v*)&PA[a0 + 8192] = mk8(lb + g * 8);
    }
    // PB: c = by+off, k = bx+kc*16+kk, val = A[c][k]
#pragma unroll
    for (int kk = 0; kk < 16; ++kk) {
        const float x = tile[off][kc * 16 + kk];
        const ushort h = bf16_rne(x); const float r1 = x - bf16_to_f(h);
        const ushort md = bf16_rne(r1); const float r2 = r1 - bf16_to_f(md);
        hb[kk] = h; mb[kk] = md; lb[kk] = bf16_rne(r2);
    }
#pragma unroll
    for (int g = 0; g < 2; ++g) {
        const size_t b0 = pb32_addr(by + off, bx + kc * 16 + g * 8, 0);
        *(ushort8v*)&PB[b0]        = mk8(hb + g * 8);
        *(ushort8v*)&PB[b0 + 4096] = mk8(mb + g * 8);
        *(ushort8v*)&PB[b0 + 8192] = mk8(lb + g * 8);
    }
}

// ---------------- split y row 0, replicated into all 128 rows of rb=0 block ----------------
__global__ void split_y(const float* __restrict__ y, ushort* YP) {
    const int t = blockIdx.x * 256 + threadIdx.x;  // 128 x 256 = 32768
    const int r = t >> 8;
    const int k0 = (t & 255) * 8;
    ushort h[8], m[8], l[8];
#pragma unroll
    for (int e = 0; e < 8; ++e) {
        const float x = y[k0 + e];
        const ushort hh = bf16_rne(x); const float r1 = x - bf16_to_f(hh);
        const ushort mm = bf16_rne(r1); const float r2 = r1 - bf16_to_f(mm);
        h[e] = hh; m[e] = mm; l[e] = bf16_rne(r2);
    }
    const size_t a0 = pa32_addr(r, k0, 0);
    *(ushort8v*)&YP[a0]        = mk8(h);
    *(ushort8v*)&YP[a0 + 4096] = mk8(m);
    *(ushort8v*)&YP[a0 + 8192] = mk8(l);
}

// ---------------- split-bf16 MFMA GEMM (+ optional fused doubling rows) ----------------
// Block 128x128, 512 thr, 8 waves = 2M x 2N x 2K, wave tile 64x64, BK=32.
// blockIdx.y < 16: squaring rows (A=Xsq, M=2048) -> PBo (+PNo) if PBo,
//   else chain-type (outF/PAout, mask r<M). blockIdx.y >= 16: doubling rows.
__global__ __launch_bounds__(512, 2)
void gemm3(const ushort* __restrict__ Xsq, const ushort* __restrict__ Xdbl,
           const ushort* __restrict__ W,
           float* __restrict__ outF, ushort* __restrict__ PAout, int ro,
           ushort* __restrict__ PNo, ushort* __restrict__ PBo,
           int M, int wantPN) {
    __shared__ __align__(16) char smem[2 * 49152];
    char* ldsc = (char*)smem;
    const int tid = threadIdx.x;
    const int w = tid >> 6, lane = tid & 63;

    const bool dbl = (blockIdx.y >= 16);
    int n0, m0;
    if (!dbl) {
        const int gy = (int)gridDim.y;
        const int nwg = 16 * (gy < 16 ? gy : 16);
        int id = blockIdx.y * 16 + blockIdx.x;
        const int cpx = nwg >> 3; id = (id & 7) * cpx + (id >> 3);
        n0 = (id & 15) * 128;
        m0 = (id >> 4) * 128;
    } else {
        const int nwg = 16 * ((int)gridDim.y - 16);
        int id = (blockIdx.y - 16) * 16 + blockIdx.x;
        const int cpx = nwg >> 3; id = (id & 7) * cpx + (id >> 3);
        n0 = (id & 15) * 128;
        m0 = (id / 16) * 128;
    }
    const ushort* X = dbl ? Xdbl : Xsq;
    const bool sq = (!dbl) && (PBo != nullptr);

    const int wk = w & 1, wn = (w >> 1) & 1, wm = w >> 2;

    // staging: per (rb,kt) A-block = 24576 B, per (cb,kt) B-block = 24576 B
    const char* gA = (const char*)X + (size_t)(m0 >> 7) * (64 * 24576) + (size_t)tid * 16;
    const char* gB = (const char*)W + (size_t)(n0 >> 7) * (64 * 24576) + (size_t)tid * 16;

    auto stage = [&](int off, int kt) {
        const char* a = gA + (size_t)kt * 24576;
        const char* b = gB + (size_t)kt * 24576;
#pragma unroll
        for (int s = 0; s < 3; ++s)
            gload16(a + s * 8192, ldsc + off + s * 8192 + w * 1024);
#pragma unroll
        for (int s = 0; s < 3; ++s)
            gload16(b + s * 8192, ldsc + off + 24576 + s * 8192 + w * 1024);
    };

    // fragment ds_read offsets: frag_base + lane*16 (conflict-free)
    int aoff[3][2], boff[3][2];
#pragma unroll
    for (int L = 0; L < 3; ++L) {
#pragma unroll
        for (int q = 0; q < 2; ++q)
            aoff[L][q] = ((L * 2 + wk) * 4 + (wm * 2 + q)) * 1024 + lane * 16;
#pragma unroll
        for (int nr = 0; nr < 2; ++nr)
            boff[L][nr] = 24576 + ((L * 2 + wk) * 4 + (wn * 2 + nr)) * 1024 + lane * 16;
    }

    f32x16 acc00 = {}, acc01 = {}, acc10 = {}, acc11 = {};

    auto compute = [&](int off) {
        short8 af[3][2], bf[3][2];
#pragma unroll
        for (int L = 0; L < 3; ++L) {
#pragma unroll
            for (int q = 0; q < 2; ++q)
                af[L][q] = *(const short8*)(ldsc + off + aoff[L][q]);
#pragma unroll
            for (int nr = 0; nr < 2; ++nr)
                bf[L][nr] = *(const short8*)(ldsc + off + boff[L][nr]);
        }
        __builtin_amdgcn_s_setprio(1);
#define PROD(La, Lb) \
        acc00 = __builtin_amdgcn_mfma_f32_32x32x16_bf16(af[La][0], bf[Lb][0], acc00, 0, 0, 0); \
        acc01 = __builtin_amdgcn_mfma_f32_32x32x16_bf16(af[La][0], bf[Lb][1], acc01, 0, 0, 0); \
        acc10 = __builtin_amdgcn_mfma_f32_32x32x16_bf16(af[La][1], bf[Lb][0], acc10, 0, 0, 0); \
        acc11 = __builtin_amdgcn_mfma_f32_32x32x16_bf16(af[La][1], bf[Lb][1], acc11, 0, 0, 0);
        PROD(2, 0) PROD(1, 1) PROD(0, 2) PROD(1, 0) PROD(0, 1) PROD(0, 0)
#undef PROD
        __builtin_amdgcn_s_setprio(0);
    };

    // pipelined K-loop: 64 steps of BK=32, 2-buffer ring, counted vmcnt
    stage(0, 0);
    for (int t = 0; t < 63; ++t) {
        stage(((t + 1) & 1) * 49152, t + 1);
        vmwait<6>();
        barfence();
        compute((t & 1) * 49152);
        lgkm0();
        barfence();
    }
    vmwait<0>();
    barfence();
    compute(49152);

    // ---- split-K reduction: wk=1 waves dump acc to LDS, wk=0 waves add ----
    barfence();  // all computes done; LDS free
    const int pr = (wm * 2 + wn) * 16384;
    if (wk == 1) {
        auto red_store = [&](const f32x16& A, int q) {
#pragma unroll
            for (int i = 0; i < 4; ++i) {
                f32x4 v = {A[i * 4 + 0], A[i * 4 + 1], A[i * 4 + 2], A[i * 4 + 3]};
                *(f32x4*)(ldsc + pr + q * 4096 + lane * 64 + i * 16) = v;
            }
        };
        red_store(acc00, 0); red_store(acc01, 1);
        red_store(acc10, 2); red_store(acc11, 3);
    }
    lgkm0();
    barfence();
    if (wk != 0) return;  // no barriers after this point
    {
        auto red_add = [&](f32x16& A, int q) {
#pragma unroll
            for (int i = 0; i < 4; ++i) {
                f32x4 v = *(const f32x4*)(ldsc + pr + q * 4096 + lane * 64 + i * 16);
                A[i * 4 + 0] += v[0]; A[i * 4 + 1] += v[1];
                A[i * 4 + 2] += v[2]; A[i * 4 + 3] += v[3];
            }
        };
        red_add(acc00, 0); red_add(acc01, 1); red_add(acc10, 2); red_add(acc11, 3);
    }

    // ---- epilogue: C/D col = lane&31, row = (reg&3) + 8*(reg>>2) + 4*(lane>>5) ----
    const int hi = lane >> 5, lc = lane & 31;
    auto do_quad = [&](const f32x16& A, int mr, int nc) {
        const int c = n0 + wn * 64 + nc * 32 + lc;
        const int rb = m0 + wm * 64 + mr * 32;
        if (sq) {
            ushort hs[16], ms[16], ls[16];
#pragma unroll
            for (int g = 0; g < 16; ++g) {
                const float v = A[g];
                const ushort h = bf16_rne(v);
                const float r1 = v - bf16_to_f(h);
                const ushort md = bf16_rne(r1);
                const float r2 = r1 - bf16_to_f(md);
                hs[g] = h; ms[g] = md; ls[g] = bf16_rne(r2);
            }
            if (wantPN) {
#pragma unroll
                for (int g = 0; g < 16; ++g) {
                    const int r = rb + (g & 3) + 8 * (g >> 2) + 4 * hi;
                    const size_t a0 = pa32_addr(r, c, 0);
                    PNo[a0] = hs[g]; PNo[a0 + 4096] = ms[g]; PNo[a0 + 8192] = ls[g];
                }
            }
#pragma unroll
            for (int g = 0; g < 4; ++g) {
                const int r0 = rb + 8 * g + 4 * hi;   // regs 4g..4g+3 -> rows r0..r0+3
                const size_t b0 = pb32_addr(c, r0, 0);
                ushort4v hv = {hs[4 * g], hs[4 * g + 1], hs[4 * g + 2], hs[4 * g + 3]};
                ushort4v mv = {ms[4 * g], ms[4 * g + 1], ms[4 * g + 2], ms[4 * g + 3]};
                ushort4v lv = {ls[4 * g], ls[4 * g + 1], ls[4 * g + 2], ls[4 * g + 3]};
                *(ushort4v*)&PBo[b0]        = hv;
                *(ushort4v*)&PBo[b0 + 4096] = mv;
                *(ushort4v*)&PBo[b0 + 8192] = lv;
            }
        } else {
#pragma unroll
            for (int g = 0; g < 16; ++g) {
                const int r = rb + (g & 3) + 8 * (g >> 2) + 4 * hi;
                if (r < M) {
                    const float v = A[g];
                    outF[(size_t)r * D + c] = v;
                    if (PAout) {
                        const ushort h = bf16_rne(v);
                        const float r1 = v - bf16_to_f(h);
                        const ushort md = bf16_rne(r1);
                        const float r2 = r1 - bf16_to_f(md);
                        const size_t a0 = pa32_addr(r + ro, c, 0);
                        PAout[a0] = h; PAout[a0 + 4096] = md;
                        PAout[a0 + 8192] = bf16_rne(r2);
                    }
                }
            }
        }
    };
    do_quad(acc00, 0, 0); do_quad(acc01, 0, 1);
    do_quad(acc10, 1, 0); do_quad(acc11, 1, 1);
}

// ================= fp32 fallback (round-1, known-good) =================
__global__ void transpose_k(const float* __restrict__ A, float* __restrict__ T) {
    __shared__ float tile[32][33];
    const int bx = blockIdx.x * 32, by = blockIdx.y * 32;
    const int tx = threadIdx.x, ty = threadIdx.y;
#pragma unroll
    for (int i = 0; i < 32; i += 8)
        tile[ty + i][tx] = A[(size_t)(by + ty + i) * D + bx + tx];
    __syncthreads();
#pragma unroll
    for (int i = 0; i < 32; i += 8)
        T[(size_t)(bx + ty + i) * D + by + tx] = tile[tx][ty + i];
}

__global__ __launch_bounds__(256) void gemm_rows(const float* __restrict__ X,
                                                 const float* __restrict__ W,
                                                 float* __restrict__ C, int M) {
    __shared__ float As[16][34];
    __shared__ float Bs[16][68];
    const int n0 = blockIdx.x * 64;
    const int m0 = blockIdx.y * 32;
    const int tid = threadIdx.x;
    const int ty = tid >> 4, tx = tid & 15;
    const int rs = tid >> 3;
    const int ks = (tid & 7) * 2;
    const int rclamp = min(m0 + rs, M - 1);
    const int kb = tid >> 4;
    const int nb = (tid & 15) * 4;
    float acc[2][4] = {{0.f, 0.f, 0.f, 0.f}, {0.f, 0.f, 0.f, 0.f}};
    for (int k0 = 0; k0 < D; k0 += 16) {
        float2 xa = *reinterpret_cast<const float2*>(&X[(size_t)rclamp * D + k0 + ks]);
        float4 wb = *reinterpret_cast<const float4*>(&W[(size_t)(k0 + kb) * D + n0 + nb]);
        As[ks][rs] = xa.x;
        As[ks + 1][rs] = xa.y;
        *reinterpret_cast<float4*>(&Bs[kb][nb]) = wb;
        __syncthreads();
#pragma unroll
        for (int kk = 0; kk < 16; ++kk) {
            float2 a = *reinterpret_cast<const float2*>(&As[kk][ty * 2]);
            float4 b = *reinterpret_cast<const float4*>(&Bs[kk][tx * 4]);
            acc[0][0] += a.x * b.x; acc[0][1] += a.x * b.y;
            acc[0][2] += a.x * b.z; acc[0][3] += a.x * b.w;
            acc[1][0] += a.y * b.x; acc[1][1] += a.y * b.y;
            acc[1][2] += a.y * b.z; acc[1][3] += a.y * b.w;
        }
        __syncthreads();
    }
#pragma unroll
    for (int i = 0; i < 2; ++i) {
        const int m = m0 + ty * 2 + i;
        if (m < M) {
            float4 v = make_float4(acc[i][0], acc[i][1], acc[i][2], acc[i][3]);
            *reinterpret_cast<float4*>(&C[(size_t)m * D + n0 + tx * 4]) = v;
        }
    }
}

__global__ __launch_bounds__(256, 2) void gemm_big(const float* __restrict__ X,
                                                   const float* __restrict__ W,
                                                   float* __restrict__ C) {
    __shared__ float As[16][132];
    __shared__ float Bs[16][68];
    const int n0 = blockIdx.x * 64;
    const int m0 = blockIdx.y * 128;
    const int tid = threadIdx.x;
    const int ty = tid >> 4, tx = tid & 15;
    const int ra = tid >> 2;
    const int ka = (tid & 3) * 4;
    const int kb = tid >> 4;
    const int nb = (tid & 15) * 4;
    float acc[8][4];
#pragma unroll
    for (int i = 0; i < 8; ++i) { acc[i][0] = 0.f; acc[i][1] = 0.f; acc[i][2] = 0.f; acc[i][3] = 0.f; }
    for (int k0 = 0; k0 < D; k0 += 16) {
        float4 a0 = *reinterpret_cast<const float4*>(&X[(size_t)(m0 + ra) * D + k0 + ka]);
        float4 a1 = *reinterpret_cast<const float4*>(&X[(size_t)(m0 + ra + 64) * D + k0 + ka]);
        float4 wb = *reinterpret_cast<const float4*>(&W[(size_t)(k0 + kb) * D + n0 + nb]);
        As[ka][ra] = a0.x; As[ka + 1][ra] = a0.y; As[ka + 2][ra] = a0.z; As[ka + 3][ra] = a0.w;
        As[ka][ra + 64] = a1.x; As[ka + 1][ra + 64] = a1.y;
        As[ka + 2][ra + 64] = a1.z; As[ka + 3][ra + 64] = a1.w;
        *reinterpret_cast<float4*>(&Bs[kb][nb]) = wb;
        __syncthreads();
#pragma unroll
        for (int kk = 0; kk < 16; ++kk) {
            float4 a04 = *reinterpret_cast<const float4*>(&As[kk][ty * 8]);
            float4 a14 = *reinterpret_cast<const float4*>(&As[kk][ty * 8 + 4]);
            float4 b4  = *reinterpret_cast<const float4*>(&Bs[kk][tx * 4]);
            const float av[8] = {a04.x, a04.y, a04.z, a04.w, a14.x, a14.y, a14.z, a14.w};
            const float bv[4] = {b4.x, b4.y, b4.z, b4.w};
#pragma unroll
            for (int i = 0; i < 8; ++i)
#pragma unroll
                for (int j = 0; j < 4; ++j)
                    acc[i][j] += av[i] * bv[j];
        }
        __syncthreads();
    }
#pragma unroll
    for (int i = 0; i < 8; ++i) {
        float4 v = make_float4(acc[i][0], acc[i][1], acc[i][2], acc[i][3]);
        *reinterpret_cast<float4*>(&C[(size_t)(m0 + ty * 8 + i) * D + n0 + tx * 4]) = v;
    }
}

__global__ void matvec_rowdot(const float* __restrict__ A, const float* __restrict__ y,
                              float* __restrict__ out) {
    const int wave = threadIdx.x >> 6, lane = threadIdx.x & 63;
    const int row = blockIdx.x * 4 + wave;
    const float* ar = A + (size_t)row * D;
    float s = 0.f;
#pragma unroll 8
    for (int k = lane; k < D; k += 64) s += ar[k] * y[k];
#pragma unroll
    for (int off = 32; off; off >>= 1) s += __shfl_down(s, off);
    if (lane == 0) out[row] = s;
}

// ================= host =================
extern "C" void kernel_launch(void* const* d_in, const int* in_sizes, int n_in,
                              void* d_out, int out_size, void* d_ws, size_t ws_size,
                              hipStream_t stream) {
    const float* A = (const float*)d_in[0];
    const float* y_init = (const float*)d_in[1];
    float* out = (float*)d_out;

    const size_t packFull = (size_t)16 * 64 * 24576;   // 24 MiB per packed matrix
    const size_t need = 5 * packFull;                  // 120 MiB

    if (ws_size >= need) {
        char* c = (char*)d_ws;
        ushort* PT[2]; ushort* PN[2]; ushort* rg[2];
        PT[0] = (ushort*)c; c += packFull;
        PT[1] = (ushort*)c; c += packFull;
        PN[0] = (ushort*)c; c += packFull;
        PN[1] = (ushort*)c; c += packFull;
        rg[0] = (ushort*)c; c += packFull;
        rg[1] = PN[0];        // dead after last squaring read (i=10 reads PN[0])
        ushort* YP = PN[1];   // read by seed before squaring i=0 writes PN[1]

        prep_pack<<<dim3(32, 32), 256, 0, stream>>>(A, PN[0], PT[0]);
        split_y<<<128, 256, 0, stream>>>(y_init, YP);

        // seed: rows[0] = y1 * T  (chain-type, M=1)
        gemm3<<<dim3(16, 1), 512, 0, stream>>>(
            YP, nullptr, PT[0], out, rg[0], 0, nullptr, nullptr, 1, 0);

        // fused squaring + doubling: i = 0..10
        int cur = 0;
        for (int i = 0; i < 11; ++i) {
            const int m = 1 << i;
            const int nd = (m + 127) / 128;
            gemm3<<<dim3(16, 16 + nd), 512, 0, stream>>>(
                PN[cur], rg[0], PT[cur],
                out + (size_t)m * D, rg[0], m,
                PN[cur ^ 1], PT[cur ^ 1],
                m, (i < 10) ? 1 : 0);
            cur ^= 1;
        }
        // cur == 1: PT[1] = T^2048

        // chain: rows[j*2048..(j+1)*2048) = rows[(j-1)*2048..) * T^2048
        for (int j = 1; j < STEPS / KB2; ++j) {
            gemm3<<<dim3(16, 16), 512, 0, stream>>>(
                rg[(j - 1) & 1], nullptr, PT[cur],
                out + (size_t)j * KB2 * D,
                (j < STEPS / KB2 - 1) ? rg[j & 1] : nullptr, 0,
                nullptr, nullptr, 2048, 0);
        }
    } else if (ws_size >= 2 * (size_t)D * D * sizeof(float)) {
        // fp32 fallback (round-1 path, known-good)
        float* Pa = (float*)d_ws;
        float* Pb = Pa + (size_t)D * D;
        transpose_k<<<dim3(D / 32, D / 32), dim3(32, 8), 0, stream>>>(A, Pa);
        gemm_rows<<<dim3(D / 64, 1), 256, 0, stream>>>(y_init, Pa, out, 1);
        float* cur = Pa;
        float* nxt = Pb;
        for (int m = 1; m < 256; m <<= 1) {
            gemm_rows<<<dim3(D / 64, (m + 31) / 32), 256, 0, stream>>>(
                out, cur, out + (size_t)m * D, m);
            gemm_big<<<dim3(D / 64, D / 128), 256, 0, stream>>>(cur, cur, nxt);
            float* t = cur; cur = nxt; nxt = t;
        }
        for (int j = 1; j < STEPS / 256; ++j) {
            gemm_rows<<<dim3(D / 64, 256 / 32), 256, 0, stream>>>(
                out + (size_t)(j - 1) * 256 * D, cur, out + (size_t)j * 256 * D, 256);
        }
    } else {
        matvec_rowdot<<<D / 4, 256, 0, stream>>>(A, y_init, out);
        for (int t = 1; t < STEPS; ++t)
            matvec_rowdot<<<D / 4, 256, 0, stream>>>(A, out + (size_t)(t - 1) * D,
                                                     out + (size_t)t * D);
    }
}

// Round 7
// 1683.694 us; speedup vs baseline: 1.3144x; 1.3144x over previous
//
#include <hip/hip_runtime.h>

// LinearRNN: ys[t] = A^(t+1) @ y_init[0], t = 0..8191, D = 2048.
// Row-vector convention: T = A^T, rows[t] = y1 * T^(t+1).
// fp32 -> 3 bf16 limbs (h,m,l); 6 limb-product MFMAs (16x16x32) ~= fp32 GEMM.
// Engine = R4's proven config: block 128x64, 512 thr, 8 waves 4Mx2N, wave tile
// 32x32, BK=32, LDS 2x36KB -> 2 blocks/CU, fragment-packed global operands,
// linear global_load_lds staging, ds_read_b128 frag_base+lane*16 (0 conflicts),
// counted vmcnt, setprio around MFMAs.
// Schedule = KB=2048: 11 fused squaring+doubling launches + 3 chain GEMMs of
// M=2048 — every heavy launch is 512+ WGs (full chip at 2 blocks/CU).

#define D 2048
#define STEPS 8192
#define KB2 2048

typedef __attribute__((ext_vector_type(8))) short short8;
typedef __attribute__((ext_vector_type(4))) float f32x4;
typedef __attribute__((ext_vector_type(4))) unsigned short ushort4v;
typedef __attribute__((ext_vector_type(8))) unsigned short ushort8v;
typedef unsigned short ushort;

__device__ __forceinline__ ushort bf16_rne(float v) {
    unsigned u = __builtin_bit_cast(unsigned, v);
    u += 0x7fffu + ((u >> 16) & 1u);
    return (ushort)(u >> 16);
}
__device__ __forceinline__ float bf16_to_f(ushort h) {
    unsigned u = (unsigned)h << 16;
    return __builtin_bit_cast(float, u);
}

// Packed-layout element addresses (in elements).
// PA (A-operand): [rb=r>>7][kt=k>>5][L][rf=(r>>4)&7][lane=(r&15)+16*((k>>3)&3)][e=k&7]
__device__ __forceinline__ size_t pa_addr(int r, int k, int L) {
    return (size_t)(((r >> 7) * 64 + (k >> 5)) * 3 + L) * 4096
         + (size_t)(((r >> 4) & 7) * 512 + ((r & 15) + 16 * ((k >> 3) & 3)) * 8 + (k & 7));
}
// PB (B-operand): [cb=c>>6][kt=k>>5][L][cf=(c>>4)&3][lane=(c&15)+16*((k>>3)&3)][e=k&7]
__device__ __forceinline__ size_t pb_addr(int c, int k, int L) {
    return (size_t)(((c >> 6) * 64 + (k >> 5)) * 3 + L) * 2048
         + (size_t)(((c >> 4) & 3) * 512 + ((c & 15) + 16 * ((k >> 3) & 3)) * 8 + (k & 7));
}

__device__ __forceinline__ ushort8v mk8(const ushort* p) {
    ushort8v v = {p[0], p[1], p[2], p[3], p[4], p[5], p[6], p[7]};
    return v;
}

__device__ __forceinline__ void gload16(const void* g, void* l) {
    __builtin_amdgcn_global_load_lds(
        (const __attribute__((address_space(1))) unsigned int*)g,
        (__attribute__((address_space(3))) unsigned int*)l, 16, 0, 0);
}

template<int N> __device__ __forceinline__ void vmwait();
template<> __device__ __forceinline__ void vmwait<0>() { asm volatile("s_waitcnt vmcnt(0)" ::: "memory"); }
template<> __device__ __forceinline__ void vmwait<4>() { asm volatile("s_waitcnt vmcnt(4)" ::: "memory"); }
template<> __device__ __forceinline__ void vmwait<5>() { asm volatile("s_waitcnt vmcnt(5)" ::: "memory"); }
__device__ __forceinline__ void lgkm0() { asm volatile("s_waitcnt lgkmcnt(0)" ::: "memory"); }
__device__ __forceinline__ void barfence() {
    __builtin_amdgcn_sched_barrier(0);
    __builtin_amdgcn_s_barrier();
    __builtin_amdgcn_sched_barrier(0);
}

// ---------------- prep: A -> PA-packed of T and PB-packed of T ----------------
// PA(r,k) = T[r][k] = A[k][r];  PB(c,k) = T[k][c] = A[c][k].
__global__ __launch_bounds__(256) void prep_pack(const float* __restrict__ A,
                                                 ushort* PA, ushort* PB) {
    __shared__ float tile[64][65];
    const int tid = threadIdx.x;
    const int bx = blockIdx.x * 64, by = blockIdx.y * 64;
    {
        const int rl = tid >> 2, cq = (tid & 3) * 16;
        const float* src = &A[(size_t)(by + rl) * D + bx + cq];
#pragma unroll
        for (int i = 0; i < 4; ++i) {
            float4 v = *reinterpret_cast<const float4*>(src + i * 4);
            tile[rl][cq + i * 4 + 0] = v.x;
            tile[rl][cq + i * 4 + 1] = v.y;
            tile[rl][cq + i * 4 + 2] = v.z;
            tile[rl][cq + i * 4 + 3] = v.w;
        }
    }
    __syncthreads();
    const int off = tid & 63, kc = tid >> 6;
    ushort hb[16], mb[16], lb[16];
    // PA: r = bx+off, k = by+kc*16+kk, val = A[k][r]
#pragma unroll
    for (int kk = 0; kk < 16; ++kk) {
        const float x = tile[kc * 16 + kk][off];
        const ushort h = bf16_rne(x); const float r1 = x - bf16_to_f(h);
        const ushort md = bf16_rne(r1); const float r2 = r1 - bf16_to_f(md);
        hb[kk] = h; mb[kk] = md; lb[kk] = bf16_rne(r2);
    }
#pragma unroll
    for (int g = 0; g < 2; ++g) {
        const size_t a0 = pa_addr(bx + off, by + kc * 16 + g * 8, 0);
        *(ushort8v*)&PA[a0]        = mk8(hb + g * 8);
        *(ushort8v*)&PA[a0 + 4096] = mk8(mb + g * 8);
        *(ushort8v*)&PA[a0 + 8192] = mk8(lb + g * 8);
    }
    // PB: c = by+off, k = bx+kc*16+kk, val = A[c][k]
#pragma unroll
    for (int kk = 0; kk < 16; ++kk) {
        const float x = tile[off][kc * 16 + kk];
        const ushort h = bf16_rne(x); const float r1 = x - bf16_to_f(h);
        const ushort md = bf16_rne(r1); const float r2 = r1 - bf16_to_f(md);
        hb[kk] = h; mb[kk] = md; lb[kk] = bf16_rne(r2);
    }
#pragma unroll
    for (int g = 0; g < 2; ++g) {
        const size_t b0 = pb_addr(by + off, bx + kc * 16 + g * 8, 0);
        *(ushort8v*)&PB[b0]        = mk8(hb + g * 8);
        *(ushort8v*)&PB[b0 + 2048] = mk8(mb + g * 8);
        *(ushort8v*)&PB[b0 + 4096] = mk8(lb + g * 8);
    }
}

// ---------------- split y row 0, replicated into all 128 rows of rb=0 block ----------------
__global__ void split_y(const float* __restrict__ y, ushort* YP) {
    const int t = blockIdx.x * 256 + threadIdx.x;  // 128 x 256 = 32768
    const int r = t >> 8;
    const int k0 = (t & 255) * 8;
    ushort h[8], m[8], l[8];
#pragma unroll
    for (int e = 0; e < 8; ++e) {
        const float x = y[k0 + e];
        const ushort hh = bf16_rne(x); const float r1 = x - bf16_to_f(hh);
        const ushort mm = bf16_rne(r1); const float r2 = r1 - bf16_to_f(mm);
        h[e] = hh; m[e] = mm; l[e] = bf16_rne(r2);
    }
    const size_t a0 = pa_addr(r, k0, 0);
    *(ushort8v*)&YP[a0]        = mk8(h);
    *(ushort8v*)&YP[a0 + 4096] = mk8(m);
    *(ushort8v*)&YP[a0 + 8192] = mk8(l);
}

// ---------------- split-bf16 MFMA GEMM (+ optional fused doubling rows) ----------------
// R4 engine: block 128x64, 512 thr, 8 waves 4Mx2N, wave tile 32x32, BK=32.
// blockIdx.y < 16: squaring-class rows (A = Xsq). If PBo != nullptr -> squaring
//   outputs (PBo always, PNo if wantPN, no row mask); else chain-type outputs
//   (outF + optional PAout at row r+ro, masked r < M).
// blockIdx.y >= 16 (fused launches): doubling rows, A = Xdbl, chain-type outputs.
__global__ __launch_bounds__(512, 4)
void gemm3(const ushort* __restrict__ Xsq, const ushort* __restrict__ Xdbl,
           const ushort* __restrict__ W,
           float* __restrict__ outF, ushort* __restrict__ PAout, int ro,
           ushort* __restrict__ PNo, ushort* __restrict__ PBo,
           int M, int wantPN) {
    __shared__ __align__(16) char smem[2 * 36864];
    char* ldsc = (char*)smem;
    const int tid = threadIdx.x;
    const int w = tid >> 6, lane = tid & 63;

    const bool dbl = (blockIdx.y >= 16);
    int n0, m0;
    if (!dbl) {
        const int gy = (int)gridDim.y;
        const int gyc = gy < 16 ? gy : 16;
        const int nwg = 32 * gyc;
        int id = blockIdx.y * 32 + blockIdx.x;
        const int cpx = nwg >> 3; id = (id & 7) * cpx + (id >> 3);
        n0 = (id & 31) * 64;
        m0 = (id >> 5) * 128;
    } else {
        const int nwg = 32 * ((int)gridDim.y - 16);
        int id = (blockIdx.y - 16) * 32 + blockIdx.x;
        const int cpx = nwg >> 3; id = (id & 7) * cpx + (id >> 3);
        n0 = (id & 31) * 64;
        m0 = (id / 32) * 128;
    }
    const ushort* X = dbl ? Xdbl : Xsq;
    const bool sq = (!dbl) && (PBo != nullptr);

    const int wm = w >> 1, wn = w & 1;   // 4M x 2N wave grid

    // staging: per (rb,kt) A-block = 24576 B, B-block = 12288 B, both linear
    const char* gA = (const char*)X + (size_t)(m0 >> 7) * (64 * 24576) + (size_t)tid * 16;
    const char* gB = (const char*)W + (size_t)(n0 >> 6) * (64 * 12288) + (size_t)tid * 16;

    auto stage = [&](int off, int kt) {
        const char* a = gA + (size_t)kt * 24576;
        const char* b = gB + (size_t)kt * 12288;
#pragma unroll
        for (int s = 0; s < 3; ++s)
            gload16(a + s * 8192, ldsc + off + s * 8192 + w * 1024);
        gload16(b, ldsc + off + 24576 + w * 1024);
        if (w < 4) gload16(b + 8192, ldsc + off + 24576 + 8192 + w * 1024);
    };

    // fragment ds_read byte offsets: frag_base + lane*16 (conflict-free)
    int aoff[3][2], boff[3][2];
#pragma unroll
    for (int L = 0; L < 3; ++L) {
#pragma unroll
        for (int q = 0; q < 2; ++q)
            aoff[L][q] = (L * 8 + wm * 2 + q) * 1024 + lane * 16;
#pragma unroll
        for (int nr = 0; nr < 2; ++nr)
            boff[L][nr] = 24576 + (L * 4 + wn * 2 + nr) * 1024 + lane * 16;
    }

    f32x4 acc[2][2] = {};

    auto compute = [&](int off) {
        short8 af[3][2], bf[3][2];
#pragma unroll
        for (int L = 0; L < 3; ++L) {
#pragma unroll
            for (int q = 0; q < 2; ++q)
                af[L][q] = *(const short8*)(ldsc + off + aoff[L][q]);
#pragma unroll
            for (int nr = 0; nr < 2; ++nr)
                bf[L][nr] = *(const short8*)(ldsc + off + boff[L][nr]);
        }
        __builtin_amdgcn_s_setprio(1);
#define PROD(La, Lb) \
        acc[0][0] = __builtin_amdgcn_mfma_f32_16x16x32_bf16(af[La][0], bf[Lb][0], acc[0][0], 0, 0, 0); \
        acc[0][1] = __builtin_amdgcn_mfma_f32_16x16x32_bf16(af[La][0], bf[Lb][1], acc[0][1], 0, 0, 0); \
        acc[1][0] = __builtin_amdgcn_mfma_f32_16x16x32_bf16(af[La][1], bf[Lb][0], acc[1][0], 0, 0, 0); \
        acc[1][1] = __builtin_amdgcn_mfma_f32_16x16x32_bf16(af[La][1], bf[Lb][1], acc[1][1], 0, 0, 0);
        PROD(2, 0) PROD(1, 1) PROD(0, 2) PROD(1, 0) PROD(0, 1) PROD(0, 0)
#undef PROD
        __builtin_amdgcn_s_setprio(0);
    };

    // pipelined K-loop: 64 steps, 2-buffer ring, counted vmcnt (never 0 in loop)
    stage(0, 0);
    for (int t = 0; t < 63; ++t) {
        stage(((t + 1) & 1) * 36864, t + 1);
        if (w < 4) vmwait<5>(); else vmwait<4>();
        barfence();
        compute((t & 1) * 36864);
        lgkm0();
        barfence();
    }
    vmwait<0>();
    barfence();
    compute(36864);

    // epilogue: C/D layout col = lane&15, row = (lane>>4)*4 + j (verified)
    const int row0 = m0 + wm * 32 + (lane >> 4) * 4;
    const int col0 = n0 + wn * 32 + (lane & 15);
#pragma unroll
    for (int mr = 0; mr < 2; ++mr) {
#pragma unroll
        for (int nr = 0; nr < 2; ++nr) {
            const int c = col0 + nr * 16;
            const int rb0 = row0 + mr * 16;
            if (sq) {
                ushort hs[4], ms[4], ls[4];
#pragma unroll
                for (int j = 0; j < 4; ++j) {
                    const float v = acc[mr][nr][j];
                    const ushort h = bf16_rne(v);
                    const float r1 = v - bf16_to_f(h);
                    const ushort md = bf16_rne(r1);
                    const float r2 = r1 - bf16_to_f(md);
                    hs[j] = h; ms[j] = md; ls[j] = bf16_rne(r2);
                    if (wantPN) {
                        const size_t a0 = pa_addr(rb0 + j, c, 0);
                        PNo[a0] = h; PNo[a0 + 4096] = md; PNo[a0 + 8192] = ls[j];
                    }
                }
                const size_t b0 = pb_addr(c, rb0, 0);
                ushort4v hv = {hs[0], hs[1], hs[2], hs[3]};
                ushort4v mv = {ms[0], ms[1], ms[2], ms[3]};
                ushort4v lv = {ls[0], ls[1], ls[2], ls[3]};
                *(ushort4v*)&PBo[b0]        = hv;
                *(ushort4v*)&PBo[b0 + 2048] = mv;
                *(ushort4v*)&PBo[b0 + 4096] = lv;
            } else {
#pragma unroll
                for (int j = 0; j < 4; ++j) {
                    const int r = rb0 + j;
                    if (r < M) {
                        const float v = acc[mr][nr][j];
                        outF[(size_t)r * D + c] = v;
                        if (PAout) {
                            const ushort h = bf16_rne(v);
                            const float r1 = v - bf16_to_f(h);
                            const ushort md = bf16_rne(r1);
                            const float r2 = r1 - bf16_to_f(md);
                            const size_t a0 = pa_addr(r + ro, c, 0);
                            PAout[a0] = h; PAout[a0 + 4096] = md;
                            PAout[a0 + 8192] = bf16_rne(r2);
                        }
                    }
                }
            }
        }
    }
}

// ================= fp32 fallback (round-1, known-good) =================
__global__ void transpose_k(const float* __restrict__ A, float* __restrict__ T) {
    __shared__ float tile[32][33];
    const int bx = blockIdx.x * 32, by = blockIdx.y * 32;
    const int tx = threadIdx.x, ty = threadIdx.y;
#pragma unroll
    for (int i = 0; i < 32; i += 8)
        tile[ty + i][tx] = A[(size_t)(by + ty + i) * D + bx + tx];
    __syncthreads();
#pragma unroll
    for (int i = 0; i < 32; i += 8)
        T[(size_t)(bx + ty + i) * D + by + tx] = tile[tx][ty + i];
}

__global__ __launch_bounds__(256) void gemm_rows(const float* __restrict__ X,
                                                 const float* __restrict__ W,
                                                 float* __restrict__ C, int M) {
    __shared__ float As[16][34];
    __shared__ float Bs[16][68];
    const int n0 = blockIdx.x * 64;
    const int m0 = blockIdx.y * 32;
    const int tid = threadIdx.x;
    const int ty = tid >> 4, tx = tid & 15;
    const int rs = tid >> 3;
    const int ks = (tid & 7) * 2;
    const int rclamp = min(m0 + rs, M - 1);
    const int kb = tid >> 4;
    const int nb = (tid & 15) * 4;
    float acc[2][4] = {{0.f, 0.f, 0.f, 0.f}, {0.f, 0.f, 0.f, 0.f}};
    for (int k0 = 0; k0 < D; k0 += 16) {
        float2 xa = *reinterpret_cast<const float2*>(&X[(size_t)rclamp * D + k0 + ks]);
        float4 wb = *reinterpret_cast<const float4*>(&W[(size_t)(k0 + kb) * D + n0 + nb]);
        As[ks][rs] = xa.x;
        As[ks + 1][rs] = xa.y;
        *reinterpret_cast<float4*>(&Bs[kb][nb]) = wb;
        __syncthreads();
#pragma unroll
        for (int kk = 0; kk < 16; ++kk) {
            float2 a = *reinterpret_cast<const float2*>(&As[kk][ty * 2]);
            float4 b = *reinterpret_cast<const float4*>(&Bs[kk][tx * 4]);
            acc[0][0] += a.x * b.x; acc[0][1] += a.x * b.y;
            acc[0][2] += a.x * b.z; acc[0][3] += a.x * b.w;
            acc[1][0] += a.y * b.x; acc[1][1] += a.y * b.y;
            acc[1][2] += a.y * b.z; acc[1][3] += a.y * b.w;
        }
        __syncthreads();
    }
#pragma unroll
    for (int i = 0; i < 2; ++i) {
        const int m = m0 + ty * 2 + i;
        if (m < M) {
            float4 v = make_float4(acc[i][0], acc[i][1], acc[i][2], acc[i][3]);
            *reinterpret_cast<float4*>(&C[(size_t)m * D + n0 + tx * 4]) = v;
        }
    }
}

__global__ __launch_bounds__(256, 2) void gemm_big(const float* __restrict__ X,
                                                   const float* __restrict__ W,
                                                   float* __restrict__ C) {
    __shared__ float As[16][132];
    __shared__ float Bs[16][68];
    const int n0 = blockIdx.x * 64;
    const int m0 = blockIdx.y * 128;
    const int tid = threadIdx.x;
    const int ty = tid >> 4, tx = tid & 15;
    const int ra = tid >> 2;
    const int ka = (tid & 3) * 4;
    const int kb = tid >> 4;
    const int nb = (tid & 15) * 4;
    float acc[8][4];
#pragma unroll
    for (int i = 0; i < 8; ++i) { acc[i][0] = 0.f; acc[i][1] = 0.f; acc[i][2] = 0.f; acc[i][3] = 0.f; }
    for (int k0 = 0; k0 < D; k0 += 16) {
        float4 a0 = *reinterpret_cast<const float4*>(&X[(size_t)(m0 + ra) * D + k0 + ka]);
        float4 a1 = *reinterpret_cast<const float4*>(&X[(size_t)(m0 + ra + 64) * D + k0 + ka]);
        float4 wb = *reinterpret_cast<const float4*>(&W[(size_t)(k0 + kb) * D + n0 + nb]);
        As[ka][ra] = a0.x; As[ka + 1][ra] = a0.y; As[ka + 2][ra] = a0.z; As[ka + 3][ra] = a0.w;
        As[ka][ra + 64] = a1.x; As[ka + 1][ra + 64] = a1.y;
        As[ka + 2][ra + 64] = a1.z; As[ka + 3][ra + 64] = a1.w;
        *reinterpret_cast<float4*>(&Bs[kb][nb]) = wb;
        __syncthreads();
#pragma unroll
        for (int kk = 0; kk < 16; ++kk) {
            float4 a04 = *reinterpret_cast<const float4*>(&As[kk][ty * 8]);
            float4 a14 = *reinterpret_cast<const float4*>(&As[kk][ty * 8 + 4]);
            float4 b4  = *reinterpret_cast<const float4*>(&Bs[kk][tx * 4]);
            const float av[8] = {a04.x, a04.y, a04.z, a04.w, a14.x, a14.y, a14.z, a14.w};
            const float bv[4] = {b4.x, b4.y, b4.z, b4.w};
#pragma unroll
            for (int i = 0; i < 8; ++i)
#pragma unroll
                for (int j = 0; j < 4; ++j)
                    acc[i][j] += av[i] * bv[j];
        }
        __syncthreads();
    }
#pragma unroll
    for (int i = 0; i < 8; ++i) {
        float4 v = make_float4(acc[i][0], acc[i][1], acc[i][2], acc[i][3]);
        *reinterpret_cast<float4*>(&C[(size_t)(m0 + ty * 8 + i) * D + n0 + tx * 4]) = v;
    }
}

__global__ void matvec_rowdot(const float* __restrict__ A, const float* __restrict__ y,
                              float* __restrict__ out) {
    const int wave = threadIdx.x >> 6, lane = threadIdx.x & 63;
    const int row = blockIdx.x * 4 + wave;
    const float* ar = A + (size_t)row * D;
    float s = 0.f;
#pragma unroll 8
    for (int k = lane; k < D; k += 64) s += ar[k] * y[k];
#pragma unroll
    for (int off = 32; off; off >>= 1) s += __shfl_down(s, off);
    if (lane == 0) out[row] = s;
}

// ================= host =================
extern "C" void kernel_launch(void* const* d_in, const int* in_sizes, int n_in,
                              void* d_out, int out_size, void* d_ws, size_t ws_size,
                              hipStream_t stream) {
    const float* A = (const float*)d_in[0];
    const float* y_init = (const float*)d_in[1];
    float* out = (float*)d_out;

    const size_t packFull = (size_t)16 * 64 * 24576;   // 24 MiB per packed matrix
    const size_t need = 5 * packFull;                  // 120 MiB

    if (ws_size >= need) {
        char* c = (char*)d_ws;
        ushort* PT[2]; ushort* PN[2]; ushort* rg[2];
        PT[0] = (ushort*)c; c += packFull;
        PT[1] = (ushort*)c; c += packFull;
        PN[0] = (ushort*)c; c += packFull;
        PN[1] = (ushort*)c; c += packFull;
        rg[0] = (ushort*)c; c += packFull;
        rg[1] = PN[0];        // last read by squaring i=10; first write chain j=1
        ushort* YP = PN[1];   // read by seed before squaring i=0 writes PN[1]

        prep_pack<<<dim3(32, 32), 256, 0, stream>>>(A, PN[0], PT[0]);
        split_y<<<128, 256, 0, stream>>>(y_init, YP);

        // seed: rows[0] = y1 * T  (chain-type, M=1)
        gemm3<<<dim3(32, 1), 512, 0, stream>>>(
            YP, nullptr, PT[0], out, rg[0], 0, nullptr, nullptr, 1, 0);

        // fused squaring + doubling: i = 0..10
        int cur = 0;
        for (int i = 0; i < 11; ++i) {
            const int m = 1 << i;
            const int nd = (m + 127) / 128;
            gemm3<<<dim3(32, 16 + nd), 512, 0, stream>>>(
                PN[cur], rg[0], PT[cur],
                out + (size_t)m * D, rg[0], m,
                PN[cur ^ 1], PT[cur ^ 1],
                m, (i < 10) ? 1 : 0);
            cur ^= 1;
        }
        // cur == 1: PT[1] = T^2048

        // chain: rows[j*2048..(j+1)*2048) = rows[(j-1)*2048..) * T^2048
        for (int j = 1; j < STEPS / KB2; ++j) {
            gemm3<<<dim3(32, 16), 512, 0, stream>>>(
                rg[(j - 1) & 1], nullptr, PT[cur],
                out + (size_t)j * KB2 * D,
                (j < STEPS / KB2 - 1) ? rg[j & 1] : nullptr, 0,
                nullptr, nullptr, 2048, 0);
        }
    } else if (ws_size >= 2 * (size_t)D * D * sizeof(float)) {
        // fp32 fallback (round-1 path, known-good)
        float* Pa = (float*)d_ws;
        float* Pb = Pa + (size_t)D * D;
        transpose_k<<<dim3(D / 32, D / 32), dim3(32, 8), 0, stream>>>(A, Pa);
        gemm_rows<<<dim3(D / 64, 1), 256, 0, stream>>>(y_init, Pa, out, 1);
        float* cur = Pa;
        float* nxt = Pb;
        for (int m = 1; m < 256; m <<= 1) {
            gemm_rows<<<dim3(D / 64, (m + 31) / 32), 256, 0, stream>>>(
                out, cur, out + (size_t)m * D, m);
            gemm_big<<<dim3(D / 64, D / 128), 256, 0, stream>>>(cur, cur, nxt);
            float* t = cur; cur = nxt; nxt = t;
        }
        for (int j = 1; j < STEPS / 256; ++j) {
            gemm_rows<<<dim3(D / 64, 256 / 32), 256, 0, stream>>>(
                out + (size_t)(j - 1) * 256 * D, cur, out + (size_t)j * 256 * D, 256);
        }
    } else {
        matvec_rowdot<<<D / 4, 256, 0, stream>>>(A, y_init, out);
        for (int t = 1; t < STEPS; ++t)
            matvec_rowdot<<<D / 4, 256, 0, stream>>>(A, out + (size_t)(t - 1) * D,
                                                     out + (size_t)t * D);
    }
}

// Round 8
// 1174.986 us; speedup vs baseline: 1.8834x; 1.4329x over previous
//
#include <hip/hip_runtime.h>

// LinearRNN: ys[t] = A^(t+1) @ y_init[0], t = 0..8191, D = 2048.
// Row-vector convention: T = A^T, rows[t] = y1 * T^(t+1).
// R8: fp16 2-limb split. x = h + m*2^-12, h=fp16(x), m=fp16((x-h)*4096).
// GEMM computes 4 limb products into 3 accumulators (hh; hm+mh; mm), combined
// in the epilogue as acc0 + acc1*2^-12 + acc2*2^-24. vs bf16 3-limb: -33% LDS
// traffic (the measured binding pipe), -33% MFMA, -33% staged bytes.
// Engine (proven R4/R7): block 128x64, 512 thr, 8 waves 4Mx2N, wave tile 32x32,
// BK=32, LDS 2x24KB -> 2 blocks/CU, fragment-packed global operands, linear
// global_load_lds staging, ds_read_b128 frag_base+lane*16 (0 conflicts),
// counted vmcnt, setprio. Schedule: 11 fused squaring+doubling + 3 chain GEMMs.

#define D 2048
#define STEPS 8192
#define KB2 2048

typedef __attribute__((ext_vector_type(8))) short short8;
typedef __attribute__((ext_vector_type(8))) _Float16 half8;
typedef __attribute__((ext_vector_type(4))) float f32x4;
typedef __attribute__((ext_vector_type(4))) unsigned short ushort4v;
typedef __attribute__((ext_vector_type(8))) unsigned short ushort8v;
typedef unsigned short ushort;

// fp16 2-limb split: x ~= h + m*2^-12  (m pre-scaled by 4096 to stay normal)
__device__ __forceinline__ void split2(float x, ushort& h, ushort& m) {
    const _Float16 hh = (_Float16)x;
    const float r = x - (float)hh;
    const _Float16 mm = (_Float16)(r * 4096.0f);
    h = __builtin_bit_cast(ushort, hh);
    m = __builtin_bit_cast(ushort, mm);
}

// Packed-layout element addresses (in elements). Fragment = 16 rows x 32 k = 1KB.
// PA: [rb=r>>7][kt=k>>5] block of 8192 elems: [L][rf=(r>>4)&7][lane][e]
__device__ __forceinline__ size_t pa_addr(int r, int k, int L) {
    return (size_t)((r >> 7) * 64 + (k >> 5)) * 8192
         + (size_t)((L * 8 + ((r >> 4) & 7)) * 512
                    + ((r & 15) + 16 * ((k >> 3) & 3)) * 8 + (k & 7));
}
// PB: [cb=c>>6][kt=k>>5] block of 4096 elems: [L][cf=(c>>4)&3][lane][e]
__device__ __forceinline__ size_t pb_addr(int c, int k, int L) {
    return (size_t)((c >> 6) * 64 + (k >> 5)) * 4096
         + (size_t)((L * 4 + ((c >> 4) & 3)) * 512
                    + ((c & 15) + 16 * ((k >> 3) & 3)) * 8 + (k & 7));
}

__device__ __forceinline__ ushort8v mk8(const ushort* p) {
    ushort8v v = {p[0], p[1], p[2], p[3], p[4], p[5], p[6], p[7]};
    return v;
}

__device__ __forceinline__ void gload16(const void* g, void* l) {
    __builtin_amdgcn_global_load_lds(
        (const __attribute__((address_space(1))) unsigned int*)g,
        (__attribute__((address_space(3))) unsigned int*)l, 16, 0, 0);
}

template<int N> __device__ __forceinline__ void vmwait();
template<> __device__ __forceinline__ void vmwait<0>() { asm volatile("s_waitcnt vmcnt(0)" ::: "memory"); }
template<> __device__ __forceinline__ void vmwait<3>() { asm volatile("s_waitcnt vmcnt(3)" ::: "memory"); }
__device__ __forceinline__ void lgkm0() { asm volatile("s_waitcnt lgkmcnt(0)" ::: "memory"); }
__device__ __forceinline__ void barfence() {
    __builtin_amdgcn_sched_barrier(0);
    __builtin_amdgcn_s_barrier();
    __builtin_amdgcn_sched_barrier(0);
}

// ---------------- prep: A -> PA-packed of T and PB-packed of T ----------------
// PA(r,k) = T[r][k] = A[k][r];  PB(c,k) = T[k][c] = A[c][k].
__global__ __launch_bounds__(256) void prep_pack(const float* __restrict__ A,
                                                 ushort* PA, ushort* PB) {
    __shared__ float tile[64][65];
    const int tid = threadIdx.x;
    const int bx = blockIdx.x * 64, by = blockIdx.y * 64;
    {
        const int rl = tid >> 2, cq = (tid & 3) * 16;
        const float* src = &A[(size_t)(by + rl) * D + bx + cq];
#pragma unroll
        for (int i = 0; i < 4; ++i) {
            float4 v = *reinterpret_cast<const float4*>(src + i * 4);
            tile[rl][cq + i * 4 + 0] = v.x;
            tile[rl][cq + i * 4 + 1] = v.y;
            tile[rl][cq + i * 4 + 2] = v.z;
            tile[rl][cq + i * 4 + 3] = v.w;
        }
    }
    __syncthreads();
    const int off = tid & 63, kc = tid >> 6;
    ushort hb[16], mb[16];
    // PA: r = bx+off, k = by+kc*16+kk, val = A[k][r]
#pragma unroll
    for (int kk = 0; kk < 16; ++kk)
        split2(tile[kc * 16 + kk][off], hb[kk], mb[kk]);
#pragma unroll
    for (int g = 0; g < 2; ++g) {
        const size_t a0 = pa_addr(bx + off, by + kc * 16 + g * 8, 0);
        *(ushort8v*)&PA[a0]        = mk8(hb + g * 8);
        *(ushort8v*)&PA[a0 + 4096] = mk8(mb + g * 8);
    }
    // PB: c = by+off, k = bx+kc*16+kk, val = A[c][k]
#pragma unroll
    for (int kk = 0; kk < 16; ++kk)
        split2(tile[off][kc * 16 + kk], hb[kk], mb[kk]);
#pragma unroll
    for (int g = 0; g < 2; ++g) {
        const size_t b0 = pb_addr(by + off, bx + kc * 16 + g * 8, 0);
        *(ushort8v*)&PB[b0]        = mk8(hb + g * 8);
        *(ushort8v*)&PB[b0 + 2048] = mk8(mb + g * 8);
    }
}

// ---------------- split y row 0, replicated into all 128 rows of rb=0 block ----------------
__global__ void split_y(const float* __restrict__ y, ushort* YP) {
    const int t = blockIdx.x * 256 + threadIdx.x;  // 128 x 256 = 32768
    const int r = t >> 8;
    const int k0 = (t & 255) * 8;
    ushort h[8], m[8];
#pragma unroll
    for (int e = 0; e < 8; ++e) split2(y[k0 + e], h[e], m[e]);
    const size_t a0 = pa_addr(r, k0, 0);
    *(ushort8v*)&YP[a0]        = mk8(h);
    *(ushort8v*)&YP[a0 + 4096] = mk8(m);
}

// ---------------- split-fp16 MFMA GEMM (+ optional fused doubling rows) ----------------
// Block 128x64, 512 thr, 8 waves 4Mx2N, wave tile 32x32, BK=32, 64 k-steps.
// LDS per buffer: A 16KB (2L x 8rf frags) + B 8KB (2L x 4cf) = 24KB, x2 = 48KB.
// blockIdx.y < 16: squaring-class rows (A = Xsq). If PBo != nullptr -> squaring
//   outputs; else chain-type (outF + optional PAout, masked r < M).
// blockIdx.y >= 16 (fused launches): doubling rows, A = Xdbl, chain-type outputs.
__global__ __launch_bounds__(512, 4)
void gemm3(const ushort* __restrict__ Xsq, const ushort* __restrict__ Xdbl,
           const ushort* __restrict__ W,
           float* __restrict__ outF, ushort* __restrict__ PAout, int ro,
           ushort* __restrict__ PNo, ushort* __restrict__ PBo,
           int M, int wantPN) {
    __shared__ __align__(16) char smem[2 * 24576];
    char* ldsc = (char*)smem;
    const int tid = threadIdx.x;
    const int w = tid >> 6, lane = tid & 63;

    const bool dbl = (blockIdx.y >= 16);
    int n0, m0;
    if (!dbl) {
        const int gy = (int)gridDim.y;
        const int gyc = gy < 16 ? gy : 16;
        const int nwg = 32 * gyc;
        int id = blockIdx.y * 32 + blockIdx.x;
        const int cpx = nwg >> 3; id = (id & 7) * cpx + (id >> 3);
        n0 = (id & 31) * 64;
        m0 = (id >> 5) * 128;
    } else {
        const int nwg = 32 * ((int)gridDim.y - 16);
        int id = (blockIdx.y - 16) * 32 + blockIdx.x;
        const int cpx = nwg >> 3; id = (id & 7) * cpx + (id >> 3);
        n0 = (id & 31) * 64;
        m0 = (id / 32) * 128;
    }
    const ushort* X = dbl ? Xdbl : Xsq;
    const bool sq = (!dbl) && (PBo != nullptr);

    const int wm = w >> 1, wn = w & 1;   // 4M x 2N wave grid

    // staging: per (rb,kt) A-block = 16384 B, B-block = 8192 B, both linear
    const char* gA = (const char*)X + (size_t)(m0 >> 7) * (64 * 16384) + (size_t)tid * 16;
    const char* gB = (const char*)W + (size_t)(n0 >> 6) * (64 * 8192) + (size_t)tid * 16;

    auto stage = [&](int off, int kt) {
        const char* a = gA + (size_t)kt * 16384;
        const char* b = gB + (size_t)kt * 8192;
        gload16(a, ldsc + off + w * 1024);
        gload16(a + 8192, ldsc + off + 8192 + w * 1024);
        gload16(b, ldsc + off + 16384 + w * 1024);
    };

    // fragment ds_read byte offsets: frag_base + lane*16 (conflict-free)
    int aoff[2][2], boff[2][2];
#pragma unroll
    for (int L = 0; L < 2; ++L) {
#pragma unroll
        for (int q = 0; q < 2; ++q)
            aoff[L][q] = (L * 8 + wm * 2 + q) * 1024 + lane * 16;
#pragma unroll
        for (int nr = 0; nr < 2; ++nr)
            boff[L][nr] = 16384 + (L * 4 + wn * 2 + nr) * 1024 + lane * 16;
    }

    f32x4 acc0[2][2] = {}, acc1[2][2] = {}, acc2[2][2] = {};

    auto compute = [&](int off) {
        short8 af[2][2], bf[2][2];
#pragma unroll
        for (int L = 0; L < 2; ++L) {
#pragma unroll
            for (int q = 0; q < 2; ++q)
                af[L][q] = *(const short8*)(ldsc + off + aoff[L][q]);
#pragma unroll
            for (int nr = 0; nr < 2; ++nr)
                bf[L][nr] = *(const short8*)(ldsc + off + boff[L][nr]);
        }
        __builtin_amdgcn_s_setprio(1);
#define H8(x) __builtin_bit_cast(half8, x)
#define MM(d, a, b) d = __builtin_amdgcn_mfma_f32_16x16x32_f16(H8(a), H8(b), d, 0, 0, 0)
#pragma unroll
        for (int i = 0; i < 2; ++i)
#pragma unroll
            for (int j = 0; j < 2; ++j) MM(acc2[i][j], af[1][i], bf[1][j]);   // m*m
#pragma unroll
        for (int i = 0; i < 2; ++i)
#pragma unroll
            for (int j = 0; j < 2; ++j) MM(acc1[i][j], af[1][i], bf[0][j]);   // m*h
#pragma unroll
        for (int i = 0; i < 2; ++i)
#pragma unroll
            for (int j = 0; j < 2; ++j) MM(acc1[i][j], af[0][i], bf[1][j]);   // h*m
#pragma unroll
        for (int i = 0; i < 2; ++i)
#pragma unroll
            for (int j = 0; j < 2; ++j) MM(acc0[i][j], af[0][i], bf[0][j]);   // h*h
#undef MM
#undef H8
        __builtin_amdgcn_s_setprio(0);
    };

    // pipelined K-loop: 64 steps, 2-buffer ring, counted vmcnt (never 0 in loop)
    stage(0, 0);
    for (int t = 0; t < 63; ++t) {
        stage(((t + 1) & 1) * 24576, t + 1);
        vmwait<3>();
        barfence();
        compute((t & 1) * 24576);
        lgkm0();
        barfence();
    }
    vmwait<0>();
    barfence();
    compute(24576);

    // epilogue: C/D layout col = lane&15, row = (lane>>4)*4 + j (verified)
    const int row0 = m0 + wm * 32 + (lane >> 4) * 4;
    const int col0 = n0 + wn * 32 + (lane & 15);
#pragma unroll
    for (int mr = 0; mr < 2; ++mr) {
#pragma unroll
        for (int nr = 0; nr < 2; ++nr) {
            const int c = col0 + nr * 16;
            const int rb0 = row0 + mr * 16;
            f32x4 vv;
#pragma unroll
            for (int j = 0; j < 4; ++j)
                vv[j] = acc0[mr][nr][j]
                      + acc1[mr][nr][j] * (1.0f / 4096.0f)
                      + acc2[mr][nr][j] * (1.0f / 16777216.0f);
            if (sq) {
                ushort hs[4], ms[4];
#pragma unroll
                for (int j = 0; j < 4; ++j) {
                    split2(vv[j], hs[j], ms[j]);
                    if (wantPN) {
                        const size_t a0 = pa_addr(rb0 + j, c, 0);
                        PNo[a0] = hs[j]; PNo[a0 + 4096] = ms[j];
                    }
                }
                const size_t b0 = pb_addr(c, rb0, 0);
                ushort4v hv = {hs[0], hs[1], hs[2], hs[3]};
                ushort4v mv = {ms[0], ms[1], ms[2], ms[3]};
                *(ushort4v*)&PBo[b0]        = hv;
                *(ushort4v*)&PBo[b0 + 2048] = mv;
            } else {
#pragma unroll
                for (int j = 0; j < 4; ++j) {
                    const int r = rb0 + j;
                    if (r < M) {
                        outF[(size_t)r * D + c] = vv[j];
                        if (PAout) {
                            ushort h, m;
                            split2(vv[j], h, m);
                            const size_t a0 = pa_addr(r + ro, c, 0);
                            PAout[a0] = h; PAout[a0 + 4096] = m;
                        }
                    }
                }
            }
        }
    }
}

// ================= fp32 fallback (round-1, known-good) =================
__global__ void transpose_k(const float* __restrict__ A, float* __restrict__ T) {
    __shared__ float tile[32][33];
    const int bx = blockIdx.x * 32, by = blockIdx.y * 32;
    const int tx = threadIdx.x, ty = threadIdx.y;
#pragma unroll
    for (int i = 0; i < 32; i += 8)
        tile[ty + i][tx] = A[(size_t)(by + ty + i) * D + bx + tx];
    __syncthreads();
#pragma unroll
    for (int i = 0; i < 32; i += 8)
        T[(size_t)(bx + ty + i) * D + by + tx] = tile[tx][ty + i];
}

__global__ __launch_bounds__(256) void gemm_rows(const float* __restrict__ X,
                                                 const float* __restrict__ W,
                                                 float* __restrict__ C, int M) {
    __shared__ float As[16][34];
    __shared__ float Bs[16][68];
    const int n0 = blockIdx.x * 64;
    const int m0 = blockIdx.y * 32;
    const int tid = threadIdx.x;
    const int ty = tid >> 4, tx = tid & 15;
    const int rs = tid >> 3;
    const int ks = (tid & 7) * 2;
    const int rclamp = min(m0 + rs, M - 1);
    const int kb = tid >> 4;
    const int nb = (tid & 15) * 4;
    float acc[2][4] = {{0.f, 0.f, 0.f, 0.f}, {0.f, 0.f, 0.f, 0.f}};
    for (int k0 = 0; k0 < D; k0 += 16) {
        float2 xa = *reinterpret_cast<const float2*>(&X[(size_t)rclamp * D + k0 + ks]);
        float4 wb = *reinterpret_cast<const float4*>(&W[(size_t)(k0 + kb) * D + n0 + nb]);
        As[ks][rs] = xa.x;
        As[ks + 1][rs] = xa.y;
        *reinterpret_cast<float4*>(&Bs[kb][nb]) = wb;
        __syncthreads();
#pragma unroll
        for (int kk = 0; kk < 16; ++kk) {
            float2 a = *reinterpret_cast<const float2*>(&As[kk][ty * 2]);
            float4 b = *reinterpret_cast<const float4*>(&Bs[kk][tx * 4]);
            acc[0][0] += a.x * b.x; acc[0][1] += a.x * b.y;
            acc[0][2] += a.x * b.z; acc[0][3] += a.x * b.w;
            acc[1][0] += a.y * b.x; acc[1][1] += a.y * b.y;
            acc[1][2] += a.y * b.z; acc[1][3] += a.y * b.w;
        }
        __syncthreads();
    }
#pragma unroll
    for (int i = 0; i < 2; ++i) {
        const int m = m0 + ty * 2 + i;
        if (m < M) {
            float4 v = make_float4(acc[i][0], acc[i][1], acc[i][2], acc[i][3]);
            *reinterpret_cast<float4*>(&C[(size_t)m * D + n0 + tx * 4]) = v;
        }
    }
}

__global__ __launch_bounds__(256, 2) void gemm_big(const float* __restrict__ X,
                                                   const float* __restrict__ W,
                                                   float* __restrict__ C) {
    __shared__ float As[16][132];
    __shared__ float Bs[16][68];
    const int n0 = blockIdx.x * 64;
    const int m0 = blockIdx.y * 128;
    const int tid = threadIdx.x;
    const int ty = tid >> 4, tx = tid & 15;
    const int ra = tid >> 2;
    const int ka = (tid & 3) * 4;
    const int kb = tid >> 4;
    const int nb = (tid & 15) * 4;
    float acc[8][4];
#pragma unroll
    for (int i = 0; i < 8; ++i) { acc[i][0] = 0.f; acc[i][1] = 0.f; acc[i][2] = 0.f; acc[i][3] = 0.f; }
    for (int k0 = 0; k0 < D; k0 += 16) {
        float4 a0 = *reinterpret_cast<const float4*>(&X[(size_t)(m0 + ra) * D + k0 + ka]);
        float4 a1 = *reinterpret_cast<const float4*>(&X[(size_t)(m0 + ra + 64) * D + k0 + ka]);
        float4 wb = *reinterpret_cast<const float4*>(&W[(size_t)(k0 + kb) * D + n0 + nb]);
        As[ka][ra] = a0.x; As[ka + 1][ra] = a0.y; As[ka + 2][ra] = a0.z; As[ka + 3][ra] = a0.w;
        As[ka][ra + 64] = a1.x; As[ka + 1][ra + 64] = a1.y;
        As[ka + 2][ra + 64] = a1.z; As[ka + 3][ra + 64] = a1.w;
        *reinterpret_cast<float4*>(&Bs[kb][nb]) = wb;
        __syncthreads();
#pragma unroll
        for (int kk = 0; kk < 16; ++kk) {
            float4 a04 = *reinterpret_cast<const float4*>(&As[kk][ty * 8]);
            float4 a14 = *reinterpret_cast<const float4*>(&As[kk][ty * 8 + 4]);
            float4 b4  = *reinterpret_cast<const float4*>(&Bs[kk][tx * 4]);
            const float av[8] = {a04.x, a04.y, a04.z, a04.w, a14.x, a14.y, a14.z, a14.w};
            const float bv[4] = {b4.x, b4.y, b4.z, b4.w};
#pragma unroll
            for (int i = 0; i < 8; ++i)
#pragma unroll
                for (int j = 0; j < 4; ++j)
                    acc[i][j] += av[i] * bv[j];
        }
        __syncthreads();
    }
#pragma unroll
    for (int i = 0; i < 8; ++i) {
        float4 v = make_float4(acc[i][0], acc[i][1], acc[i][2], acc[i][3]);
        *reinterpret_cast<float4*>(&C[(size_t)(m0 + ty * 8 + i) * D + n0 + tx * 4]) = v;
    }
}

__global__ void matvec_rowdot(const float* __restrict__ A, const float* __restrict__ y,
                              float* __restrict__ out) {
    const int wave = threadIdx.x >> 6, lane = threadIdx.x & 63;
    const int row = blockIdx.x * 4 + wave;
    const float* ar = A + (size_t)row * D;
    float s = 0.f;
#pragma unroll 8
    for (int k = lane; k < D; k += 64) s += ar[k] * y[k];
#pragma unroll
    for (int off = 32; off; off >>= 1) s += __shfl_down(s, off);
    if (lane == 0) out[row] = s;
}

// ================= host =================
extern "C" void kernel_launch(void* const* d_in, const int* in_sizes, int n_in,
                              void* d_out, int out_size, void* d_ws, size_t ws_size,
                              hipStream_t stream) {
    const float* A = (const float*)d_in[0];
    const float* y_init = (const float*)d_in[1];
    float* out = (float*)d_out;

    const size_t packFull = (size_t)16 * 64 * 16384;   // 16 MiB per packed matrix
    const size_t need = 5 * packFull;                  // 80 MiB

    if (ws_size >= need) {
        char* c = (char*)d_ws;
        ushort* PT[2]; ushort* PN[2]; ushort* rg[2];
        PT[0] = (ushort*)c; c += packFull;
        PT[1] = (ushort*)c; c += packFull;
        PN[0] = (ushort*)c; c += packFull;
        PN[1] = (ushort*)c; c += packFull;
        rg[0] = (ushort*)c; c += packFull;
        rg[1] = PN[0];        // last read by squaring i=10; first write chain j=1
        ushort* YP = PN[1];   // read by seed before squaring i=0 writes PN[1]

        prep_pack<<<dim3(32, 32), 256, 0, stream>>>(A, PN[0], PT[0]);
        split_y<<<128, 256, 0, stream>>>(y_init, YP);

        // seed: rows[0] = y1 * T  (chain-type, M=1)
        gemm3<<<dim3(32, 1), 512, 0, stream>>>(
            YP, nullptr, PT[0], out, rg[0], 0, nullptr, nullptr, 1, 0);

        // fused squaring + doubling: i = 0..10
        int cur = 0;
        for (int i = 0; i < 11; ++i) {
            const int m = 1 << i;
            const int nd = (m + 127) / 128;
            gemm3<<<dim3(32, 16 + nd), 512, 0, stream>>>(
                PN[cur], rg[0], PT[cur],
                out + (size_t)m * D, rg[0], m,
                PN[cur ^ 1], PT[cur ^ 1],
                m, (i < 10) ? 1 : 0);
            cur ^= 1;
        }
        // cur == 1: PT[1] = T^2048

        // chain: rows[j*2048..(j+1)*2048) = rows[(j-1)*2048..) * T^2048
        for (int j = 1; j < STEPS / KB2; ++j) {
            gemm3<<<dim3(32, 16), 512, 0, stream>>>(
                rg[(j - 1) & 1], nullptr, PT[cur],
                out + (size_t)j * KB2 * D,
                (j < STEPS / KB2 - 1) ? rg[j & 1] : nullptr, 0,
                nullptr, nullptr, 2048, 0);
        }
    } else if (ws_size >= 2 * (size_t)D * D * sizeof(float)) {
        // fp32 fallback (round-1 path, known-good)
        float* Pa = (float*)d_ws;
        float* Pb = Pa + (size_t)D * D;
        transpose_k<<<dim3(D / 32, D / 32), dim3(32, 8), 0, stream>>>(A, Pa);
        gemm_rows<<<dim3(D / 64, 1), 256, 0, stream>>>(y_init, Pa, out, 1);
        float* cur = Pa;
        float* nxt = Pb;
        for (int m = 1; m < 256; m <<= 1) {
            gemm_rows<<<dim3(D / 64, (m + 31) / 32), 256, 0, stream>>>(
                out, cur, out + (size_t)m * D, m);
            gemm_big<<<dim3(D / 64, D / 128), 256, 0, stream>>>(cur, cur, nxt);
            float* t = cur; cur = nxt; nxt = t;
        }
        for (int j = 1; j < STEPS / 256; ++j) {
            gemm_rows<<<dim3(D / 64, 256 / 32), 256, 0, stream>>>(
                out + (size_t)(j - 1) * 256 * D, cur, out + (size_t)j * 256 * D, 256);
        }
    } else {
        matvec_rowdot<<<D / 4, 256, 0, stream>>>(A, y_init, out);
        for (int t = 1; t < STEPS; ++t)
            matvec_rowdot<<<D / 4, 256, 0, stream>>>(A, out + (size_t)(t - 1) * D,
                                                     out + (size_t)t * D);
    }
}

// Round 9
// 1113.512 us; speedup vs baseline: 1.9874x; 1.0552x over previous
//
#include <hip/hip_runtime.h>

// LinearRNN: ys[t] = A^(t+1) @ y_init[0], t = 0..8191, D = 2048.
// Row-vector convention: T = A^T, rows[t] = y1 * T^(t+1).
// fp16 2-limb split: x = h + m*2^-12. 4 limb products into 3 accumulators
// (hh; hm+mh; mm), combined as acc0 + acc1*2^-12 + acc2*2^-24.
// Engine: block 128x64, 512 thr, 8 waves 4Mx2N, wave tile 32x32, BK=32,
// fragment-packed global operands, linear global_load_lds staging,
// ds_read_b128 frag_base+lane*16 (0 conflicts), setprio around MFMAs.
// R9: K-loop = 3-buffer ring (3x24KB = 72KB, 2 blocks/CU), ONE barrier per
// k-step, depth-2 prefetch (vmcnt(3) steady state), stage issued after the
// barrier so gload_lds writes overlap MFMA. Ring distance 2 makes the single
// barrier safe: stage(t+3) hits buf[t%3] only after barrier(t+1), which the
// slowest wave passes only after retiring compute(t).
// Schedule: 11 fused squaring+doubling launches + 3 chain GEMMs of M=2048.

#define D 2048
#define STEPS 8192
#define KB2 2048

typedef __attribute__((ext_vector_type(8))) short short8;
typedef __attribute__((ext_vector_type(8))) _Float16 half8;
typedef __attribute__((ext_vector_type(4))) float f32x4;
typedef __attribute__((ext_vector_type(4))) unsigned short ushort4v;
typedef __attribute__((ext_vector_type(8))) unsigned short ushort8v;
typedef unsigned short ushort;

// fp16 2-limb split: x ~= h + m*2^-12  (m pre-scaled by 4096 to stay normal)
__device__ __forceinline__ void split2(float x, ushort& h, ushort& m) {
    const _Float16 hh = (_Float16)x;
    const float r = x - (float)hh;
    const _Float16 mm = (_Float16)(r * 4096.0f);
    h = __builtin_bit_cast(ushort, hh);
    m = __builtin_bit_cast(ushort, mm);
}

// Packed-layout element addresses (in elements). Fragment = 16 rows x 32 k = 1KB.
// PA: [rb=r>>7][kt=k>>5] block of 8192 elems: [L][rf=(r>>4)&7][lane][e]
__device__ __forceinline__ size_t pa_addr(int r, int k, int L) {
    return (size_t)((r >> 7) * 64 + (k >> 5)) * 8192
         + (size_t)((L * 8 + ((r >> 4) & 7)) * 512
                    + ((r & 15) + 16 * ((k >> 3) & 3)) * 8 + (k & 7));
}
// PB: [cb=c>>6][kt=k>>5] block of 4096 elems: [L][cf=(c>>4)&3][lane][e]
__device__ __forceinline__ size_t pb_addr(int c, int k, int L) {
    return (size_t)((c >> 6) * 64 + (k >> 5)) * 4096
         + (size_t)((L * 4 + ((c >> 4) & 3)) * 512
                    + ((c & 15) + 16 * ((k >> 3) & 3)) * 8 + (k & 7));
}

__device__ __forceinline__ ushort8v mk8(const ushort* p) {
    ushort8v v = {p[0], p[1], p[2], p[3], p[4], p[5], p[6], p[7]};
    return v;
}

__device__ __forceinline__ void gload16(const void* g, void* l) {
    __builtin_amdgcn_global_load_lds(
        (const __attribute__((address_space(1))) unsigned int*)g,
        (__attribute__((address_space(3))) unsigned int*)l, 16, 0, 0);
}

template<int N> __device__ __forceinline__ void vmwait();
template<> __device__ __forceinline__ void vmwait<0>() { asm volatile("s_waitcnt vmcnt(0)" ::: "memory"); }
template<> __device__ __forceinline__ void vmwait<3>() { asm volatile("s_waitcnt vmcnt(3)" ::: "memory"); }
__device__ __forceinline__ void barfence() {
    __builtin_amdgcn_sched_barrier(0);
    __builtin_amdgcn_s_barrier();
    __builtin_amdgcn_sched_barrier(0);
}

// ---------------- prep: A -> PA-packed of T and PB-packed of T ----------------
// PA(r,k) = T[r][k] = A[k][r];  PB(c,k) = T[k][c] = A[c][k].
__global__ __launch_bounds__(256) void prep_pack(const float* __restrict__ A,
                                                 ushort* PA, ushort* PB) {
    __shared__ float tile[64][65];
    const int tid = threadIdx.x;
    const int bx = blockIdx.x * 64, by = blockIdx.y * 64;
    {
        const int rl = tid >> 2, cq = (tid & 3) * 16;
        const float* src = &A[(size_t)(by + rl) * D + bx + cq];
#pragma unroll
        for (int i = 0; i < 4; ++i) {
            float4 v = *reinterpret_cast<const float4*>(src + i * 4);
            tile[rl][cq + i * 4 + 0] = v.x;
            tile[rl][cq + i * 4 + 1] = v.y;
            tile[rl][cq + i * 4 + 2] = v.z;
            tile[rl][cq + i * 4 + 3] = v.w;
        }
    }
    __syncthreads();
    const int off = tid & 63, kc = tid >> 6;
    ushort hb[16], mb[16];
    // PA: r = bx+off, k = by+kc*16+kk, val = A[k][r]
#pragma unroll
    for (int kk = 0; kk < 16; ++kk)
        split2(tile[kc * 16 + kk][off], hb[kk], mb[kk]);
#pragma unroll
    for (int g = 0; g < 2; ++g) {
        const size_t a0 = pa_addr(bx + off, by + kc * 16 + g * 8, 0);
        *(ushort8v*)&PA[a0]        = mk8(hb + g * 8);
        *(ushort8v*)&PA[a0 + 4096] = mk8(mb + g * 8);
    }
    // PB: c = by+off, k = bx+kc*16+kk, val = A[c][k]
#pragma unroll
    for (int kk = 0; kk < 16; ++kk)
        split2(tile[off][kc * 16 + kk], hb[kk], mb[kk]);
#pragma unroll
    for (int g = 0; g < 2; ++g) {
        const size_t b0 = pb_addr(by + off, bx + kc * 16 + g * 8, 0);
        *(ushort8v*)&PB[b0]        = mk8(hb + g * 8);
        *(ushort8v*)&PB[b0 + 2048] = mk8(mb + g * 8);
    }
}

// ---------------- split y row 0, replicated into all 128 rows of rb=0 block ----------------
__global__ void split_y(const float* __restrict__ y, ushort* YP) {
    const int t = blockIdx.x * 256 + threadIdx.x;  // 128 x 256 = 32768
    const int r = t >> 8;
    const int k0 = (t & 255) * 8;
    ushort h[8], m[8];
#pragma unroll
    for (int e = 0; e < 8; ++e) split2(y[k0 + e], h[e], m[e]);
    const size_t a0 = pa_addr(r, k0, 0);
    *(ushort8v*)&YP[a0]        = mk8(h);
    *(ushort8v*)&YP[a0 + 4096] = mk8(m);
}

// ---------------- split-fp16 MFMA GEMM (+ optional fused doubling rows) ----------------
// Block 128x64, 512 thr, 8 waves 4Mx2N, wave tile 32x32, BK=32, 64 k-steps.
// LDS: 3 buffers x 24KB (A 16KB + B 8KB) = 72KB -> 2 blocks/CU.
// blockIdx.y < 16: squaring-class rows (A = Xsq). If PBo != nullptr -> squaring
//   outputs; else chain-type (outF + optional PAout, masked r < M).
// blockIdx.y >= 16 (fused launches): doubling rows, A = Xdbl, chain-type outputs.
__global__ __launch_bounds__(512, 4)
void gemm3(const ushort* __restrict__ Xsq, const ushort* __restrict__ Xdbl,
           const ushort* __restrict__ W,
           float* __restrict__ outF, ushort* __restrict__ PAout, int ro,
           ushort* __restrict__ PNo, ushort* __restrict__ PBo,
           int M, int wantPN) {
    __shared__ __align__(16) char smem[3 * 24576];
    char* ldsc = (char*)smem;
    const int tid = threadIdx.x;
    const int w = tid >> 6, lane = tid & 63;

    const bool dbl = (blockIdx.y >= 16);
    int n0, m0;
    if (!dbl) {
        const int gy = (int)gridDim.y;
        const int gyc = gy < 16 ? gy : 16;
        const int nwg = 32 * gyc;
        int id = blockIdx.y * 32 + blockIdx.x;
        const int cpx = nwg >> 3; id = (id & 7) * cpx + (id >> 3);
        n0 = (id & 31) * 64;
        m0 = (id >> 5) * 128;
    } else {
        const int nwg = 32 * ((int)gridDim.y - 16);
        int id = (blockIdx.y - 16) * 32 + blockIdx.x;
        const int cpx = nwg >> 3; id = (id & 7) * cpx + (id >> 3);
        n0 = (id & 31) * 64;
        m0 = (id / 32) * 128;
    }
    const ushort* X = dbl ? Xdbl : Xsq;
    const bool sq = (!dbl) && (PBo != nullptr);

    const int wm = w >> 1, wn = w & 1;   // 4M x 2N wave grid

    // staging: per (rb,kt) A-block = 16384 B, B-block = 8192 B, both linear
    const char* gA = (const char*)X + (size_t)(m0 >> 7) * (64 * 16384) + (size_t)tid * 16;
    const char* gB = (const char*)W + (size_t)(n0 >> 6) * (64 * 8192) + (size_t)tid * 16;

    auto stage = [&](int off, int kt) {
        const char* a = gA + (size_t)kt * 16384;
        const char* b = gB + (size_t)kt * 8192;
        gload16(a, ldsc + off + w * 1024);
        gload16(a + 8192, ldsc + off + 8192 + w * 1024);
        gload16(b, ldsc + off + 16384 + w * 1024);
    };

    // fragment ds_read byte offsets: frag_base + lane*16 (conflict-free)
    int aoff[2][2], boff[2][2];
#pragma unroll
    for (int L = 0; L < 2; ++L) {
#pragma unroll
        for (int q = 0; q < 2; ++q)
            aoff[L][q] = (L * 8 + wm * 2 + q) * 1024 + lane * 16;
#pragma unroll
        for (int nr = 0; nr < 2; ++nr)
            boff[L][nr] = 16384 + (L * 4 + wn * 2 + nr) * 1024 + lane * 16;
    }

    f32x4 acc0[2][2] = {}, acc1[2][2] = {}, acc2[2][2] = {};

    auto compute = [&](int off) {
        short8 af[2][2], bf[2][2];
#pragma unroll
        for (int L = 0; L < 2; ++L) {
#pragma unroll
            for (int q = 0; q < 2; ++q)
                af[L][q] = *(const short8*)(ldsc + off + aoff[L][q]);
#pragma unroll
            for (int nr = 0; nr < 2; ++nr)
                bf[L][nr] = *(const short8*)(ldsc + off + boff[L][nr]);
        }
        __builtin_amdgcn_s_setprio(1);
#define H8(x) __builtin_bit_cast(half8, x)
#define MM(d, a, b) d = __builtin_amdgcn_mfma_f32_16x16x32_f16(H8(a), H8(b), d, 0, 0, 0)
#pragma unroll
        for (int i = 0; i < 2; ++i)
#pragma unroll
            for (int j = 0; j < 2; ++j) MM(acc2[i][j], af[1][i], bf[1][j]);   // m*m
#pragma unroll
        for (int i = 0; i < 2; ++i)
#pragma unroll
            for (int j = 0; j < 2; ++j) MM(acc1[i][j], af[1][i], bf[0][j]);   // m*h
#pragma unroll
        for (int i = 0; i < 2; ++i)
#pragma unroll
            for (int j = 0; j < 2; ++j) MM(acc1[i][j], af[0][i], bf[1][j]);   // h*m
#pragma unroll
        for (int i = 0; i < 2; ++i)
#pragma unroll
            for (int j = 0; j < 2; ++j) MM(acc0[i][j], af[0][i], bf[0][j]);   // h*h
#undef MM
#undef H8
        __builtin_amdgcn_s_setprio(0);
    };

    // ---- K-loop: 3-buffer ring, ONE barrier/step, depth-2 prefetch ----
    // body t: vmwait(3) [stage(t) landed]; barrier; stage(t+2); compute(t).
    // Safe: stage(t+2)->buf[(t+2)%3] issued after barrier(t); slowest wave
    // passed barrier(t) only after retiring compute(t-1) (= last reader of
    // that buffer). Steady-state vmcnt(3) keeps stage(t+1) in flight.
    stage(0, 0);
    stage(24576, 1);
    int cb = 0, nb2 = 49152;           // buf of t, buf of t+2
    for (int t = 0; t < 62; ++t) {
        vmwait<3>();
        barfence();
        stage(nb2, t + 2);
        compute(cb);
        const int tmp = cb;
        cb = (cb == 49152) ? 0 : cb + 24576;
        nb2 = (tmp == 0) ? 0 + 0 : nb2;            // recompute below
        nb2 = (cb == 0) ? 49152 : cb - 24576 + 49152;  // placeholder, fixed next line
        nb2 = tmp;                                  // buf[t] becomes buf[t+3]... 
    }
    // NOTE: the ring bookkeeping above is intentionally simplified:
    // buf indices cycle 0,1,2; buf[(t+2)%3] == buf[(t-1)%3] == previous cb.
    // The three assignments collapse to: new nb2 = old cb. (Kept explicit.)
    vmwait<3>();
    barfence();
    compute(cb);                        // t = 62
    cb = (cb == 49152) ? 0 : cb + 24576;
    vmwait<0>();
    barfence();
    compute(cb);                        // t = 63

    // epilogue: C/D layout col = lane&15, row = (lane>>4)*4 + j (verified)
    const int row0 = m0 + wm * 32 + (lane >> 4) * 4;
    const int col0 = n0 + wn * 32 + (lane & 15);
#pragma unroll
    for (int mr = 0; mr < 2; ++mr) {
#pragma unroll
        for (int nr = 0; nr < 2; ++nr) {
            const int c = col0 + nr * 16;
            const int rb0 = row0 + mr * 16;
            f32x4 vv;
#pragma unroll
            for (int j = 0; j < 4; ++j)
                vv[j] = acc0[mr][nr][j]
                      + acc1[mr][nr][j] * (1.0f / 4096.0f)
                      + acc2[mr][nr][j] * (1.0f / 16777216.0f);
            if (sq) {
                ushort hs[4], ms[4];
#pragma unroll
                for (int j = 0; j < 4; ++j) {
                    split2(vv[j], hs[j], ms[j]);
                    if (wantPN) {
                        const size_t a0 = pa_addr(rb0 + j, c, 0);
                        PNo[a0] = hs[j]; PNo[a0 + 4096] = ms[j];
                    }
                }
                const size_t b0 = pb_addr(c, rb0, 0);
                ushort4v hv = {hs[0], hs[1], hs[2], hs[3]};
                ushort4v mv = {ms[0], ms[1], ms[2], ms[3]};
                *(ushort4v*)&PBo[b0]        = hv;
                *(ushort4v*)&PBo[b0 + 2048] = mv;
            } else {
#pragma unroll
                for (int j = 0; j < 4; ++j) {
                    const int r = rb0 + j;
                    if (r < M) {
                        outF[(size_t)r * D + c] = vv[j];
                        if (PAout) {
                            ushort h, m;
                            split2(vv[j], h, m);
                            const size_t a0 = pa_addr(r + ro, c, 0);
                            PAout[a0] = h; PAout[a0 + 4096] = m;
                        }
                    }
                }
            }
        }
    }
}

// ================= fp32 fallback (round-1, known-good) =================
__global__ void transpose_k(const float* __restrict__ A, float* __restrict__ T) {
    __shared__ float tile[32][33];
    const int bx = blockIdx.x * 32, by = blockIdx.y * 32;
    const int tx = threadIdx.x, ty = threadIdx.y;
#pragma unroll
    for (int i = 0; i < 32; i += 8)
        tile[ty + i][tx] = A[(size_t)(by + ty + i) * D + bx + tx];
    __syncthreads();
#pragma unroll
    for (int i = 0; i < 32; i += 8)
        T[(size_t)(bx + ty + i) * D + by + tx] = tile[tx][ty + i];
}

__global__ __launch_bounds__(256) void gemm_rows(const float* __restrict__ X,
                                                 const float* __restrict__ W,
                                                 float* __restrict__ C, int M) {
    __shared__ float As[16][34];
    __shared__ float Bs[16][68];
    const int n0 = blockIdx.x * 64;
    const int m0 = blockIdx.y * 32;
    const int tid = threadIdx.x;
    const int ty = tid >> 4, tx = tid & 15;
    const int rs = tid >> 3;
    const int ks = (tid & 7) * 2;
    const int rclamp = min(m0 + rs, M - 1);
    const int kb = tid >> 4;
    const int nb = (tid & 15) * 4;
    float acc[2][4] = {{0.f, 0.f, 0.f, 0.f}, {0.f, 0.f, 0.f, 0.f}};
    for (int k0 = 0; k0 < D; k0 += 16) {
        float2 xa = *reinterpret_cast<const float2*>(&X[(size_t)rclamp * D + k0 + ks]);
        float4 wb = *reinterpret_cast<const float4*>(&W[(size_t)(k0 + kb) * D + n0 + nb]);
        As[ks][rs] = xa.x;
        As[ks + 1][rs] = xa.y;
        *reinterpret_cast<float4*>(&Bs[kb][nb]) = wb;
        __syncthreads();
#pragma unroll
        for (int kk = 0; kk < 16; ++kk) {
            float2 a = *reinterpret_cast<const float2*>(&As[kk][ty * 2]);
            float4 b = *reinterpret_cast<const float4*>(&Bs[kk][tx * 4]);
            acc[0][0] += a.x * b.x; acc[0][1] += a.x * b.y;
            acc[0][2] += a.x * b.z; acc[0][3] += a.x * b.w;
            acc[1][0] += a.y * b.x; acc[1][1] += a.y * b.y;
            acc[1][2] += a.y * b.z; acc[1][3] += a.y * b.w;
        }
        __syncthreads();
    }
#pragma unroll
    for (int i = 0; i < 2; ++i) {
        const int m = m0 + ty * 2 + i;
        if (m < M) {
            float4 v = make_float4(acc[i][0], acc[i][1], acc[i][2], acc[i][3]);
            *reinterpret_cast<float4*>(&C[(size_t)m * D + n0 + tx * 4]) = v;
        }
    }
}

__global__ __launch_bounds__(256, 2) void gemm_big(const float* __restrict__ X,
                                                   const float* __restrict__ W,
                                                   float* __restrict__ C) {
    __shared__ float As[16][132];
    __shared__ float Bs[16][68];
    const int n0 = blockIdx.x * 64;
    const int m0 = blockIdx.y * 128;
    const int tid = threadIdx.x;
    const int ty = tid >> 4, tx = tid & 15;
    const int ra = tid >> 2;
    const int ka = (tid & 3) * 4;
    const int kb = tid >> 4;
    const int nb = (tid & 15) * 4;
    float acc[8][4];
#pragma unroll
    for (int i = 0; i < 8; ++i) { acc[i][0] = 0.f; acc[i][1] = 0.f; acc[i][2] = 0.f; acc[i][3] = 0.f; }
    for (int k0 = 0; k0 < D; k0 += 16) {
        float4 a0 = *reinterpret_cast<const float4*>(&X[(size_t)(m0 + ra) * D + k0 + ka]);
        float4 a1 = *reinterpret_cast<const float4*>(&X[(size_t)(m0 + ra + 64) * D + k0 + ka]);
        float4 wb = *reinterpret_cast<const float4*>(&W[(size_t)(k0 + kb) * D + n0 + nb]);
        As[ka][ra] = a0.x; As[ka + 1][ra] = a0.y; As[ka + 2][ra] = a0.z; As[ka + 3][ra] = a0.w;
        As[ka][ra + 64] = a1.x; As[ka + 1][ra + 64] = a1.y;
        As[ka + 2][ra + 64] = a1.z; As[ka + 3][ra + 64] = a1.w;
        *reinterpret_cast<float4*>(&Bs[kb][nb]) = wb;
        __syncthreads();
#pragma unroll
        for (int kk = 0; kk < 16; ++kk) {
            float4 a04 = *reinterpret_cast<const float4*>(&As[kk][ty * 8]);
            float4 a14 = *reinterpret_cast<const float4*>(&As[kk][ty * 8 + 4]);
            float4 b4  = *reinterpret_cast<const float4*>(&Bs[kk][tx * 4]);
            const float av[8] = {a04.x, a04.y, a04.z, a04.w, a14.x, a14.y, a14.z, a14.w};
            const float bv[4] = {b4.x, b4.y, b4.z, b4.w};
#pragma unroll
            for (int i = 0; i < 8; ++i)
#pragma unroll
                for (int j = 0; j < 4; ++j)
                    acc[i][j] += av[i] * bv[j];
        }
        __syncthreads();
    }
#pragma unroll
    for (int i = 0; i < 8; ++i) {
        float4 v = make_float4(acc[i][0], acc[i][1], acc[i][2], acc[i][3]);
        *reinterpret_cast<float4*>(&C[(size_t)(m0 + ty * 8 + i) * D + n0 + tx * 4]) = v;
    }
}

__global__ void matvec_rowdot(const float* __restrict__ A, const float* __restrict__ y,
                              float* __restrict__ out) {
    const int wave = threadIdx.x >> 6, lane = threadIdx.x & 63;
    const int row = blockIdx.x * 4 + wave;
    const float* ar = A + (size_t)row * D;
    float s = 0.f;
#pragma unroll 8
    for (int k = lane; k < D; k += 64) s += ar[k] * y[k];
#pragma unroll
    for (int off = 32; off; off >>= 1) s += __shfl_down(s, off);
    if (lane == 0) out[row] = s;
}

// ================= host =================
extern "C" void kernel_launch(void* const* d_in, const int* in_sizes, int n_in,
                              void* d_out, int out_size, void* d_ws, size_t ws_size,
                              hipStream_t stream) {
    const float* A = (const float*)d_in[0];
    const float* y_init = (const float*)d_in[1];
    float* out = (float*)d_out;

    const size_t packFull = (size_t)16 * 64 * 16384;   // 16 MiB per packed matrix
    const size_t need = 5 * packFull;                  // 80 MiB

    if (ws_size >= need) {
        char* c = (char*)d_ws;
        ushort* PT[2]; ushort* PN[2]; ushort* rg[2];
        PT[0] = (ushort*)c; c += packFull;
        PT[1] = (ushort*)c; c += packFull;
        PN[0] = (ushort*)c; c += packFull;
        PN[1] = (ushort*)c; c += packFull;
        rg[0] = (ushort*)c; c += packFull;
        rg[1] = PN[0];        // last read by squaring i=10; first write chain j=1
        ushort* YP = PN[1];   // read by seed before squaring i=0 writes PN[1]

        prep_pack<<<dim3(32, 32), 256, 0, stream>>>(A, PN[0], PT[0]);
        split_y<<<128, 256, 0, stream>>>(y_init, YP);

        // seed: rows[0] = y1 * T  (chain-type, M=1)
        gemm3<<<dim3(32, 1), 512, 0, stream>>>(
            YP, nullptr, PT[0], out, rg[0], 0, nullptr, nullptr, 1, 0);

        // fused squaring + doubling: i = 0..10
        int cur = 0;
        for (int i = 0; i < 11; ++i) {
            const int m = 1 << i;
            const int nd = (m + 127) / 128;
            gemm3<<<dim3(32, 16 + nd), 512, 0, stream>>>(
                PN[cur], rg[0], PT[cur],
                out + (size_t)m * D, rg[0], m,
                PN[cur ^ 1], PT[cur ^ 1],
                m, (i < 10) ? 1 : 0);
            cur ^= 1;
        }
        // cur == 1: PT[1] = T^2048

        // chain: rows[j*2048..(j+1)*2048) = rows[(j-1)*2048..) * T^2048
        for (int j = 1; j < STEPS / KB2; ++j) {
            gemm3<<<dim3(32, 16), 512, 0, stream>>>(
                rg[(j - 1) & 1], nullptr, PT[cur],
                out + (size_t)j * KB2 * D,
                (j < STEPS / KB2 - 1) ? rg[j & 1] : nullptr, 0,
                nullptr, nullptr, 2048, 0);
        }
    } else if (ws_size >= 2 * (size_t)D * D * sizeof(float)) {
        // fp32 fallback (round-1 path, known-good)
        float* Pa = (float*)d_ws;
        float* Pb = Pa + (size_t)D * D;
        transpose_k<<<dim3(D / 32, D / 32), dim3(32, 8), 0, stream>>>(A, Pa);
        gemm_rows<<<dim3(D / 64, 1), 256, 0, stream>>>(y_init, Pa, out, 1);
        float* cur = Pa;
        float* nxt = Pb;
        for (int m = 1; m < 256; m <<= 1) {
            gemm_rows<<<dim3(D / 64, (m + 31) / 32), 256, 0, stream>>>(
                out, cur, out + (size_t)m * D, m);
            gemm_big<<<dim3(D / 64, D / 128), 256, 0, stream>>>(cur, cur, nxt);
            float* t = cur; cur = nxt; nxt = t;
        }
        for (int j = 1; j < STEPS / 256; ++j) {
            gemm_rows<<<dim3(D / 64, 256 / 32), 256, 0, stream>>>(
                out + (size_t)(j - 1) * 256 * D, cur, out + (size_t)j * 256 * D, 256);
        }
    } else {
        matvec_rowdot<<<D / 4, 256, 0, stream>>>(A, y_init, out);
        for (int t = 1; t < STEPS; ++t)
            matvec_rowdot<<<D / 4, 256, 0, stream>>>(A, out + (size_t)(t - 1) * D,
                                                     out + (size_t)t * D);
    }
}